// Round 3
// baseline (237.120 us; speedup 1.0000x reference)
//
#include <hip/hip_runtime.h>
#include <cmath>

#define NL 512
#define SS 10
#define DD 128
#define HWC (128 * 128)

typedef short bf16x8 __attribute__((ext_vector_type(8)));
typedef float f32x4 __attribute__((ext_vector_type(4)));

// ---------------- transpose (D, HW) -> (HW, D), both images ----------------
__global__ __launch_bounds__(256) void transpose_kernel(
    const float* __restrict__ in1, const float* __restrict__ in2,
    float* __restrict__ out1, float* __restrict__ out2)
{
    const float* in = blockIdx.z ? in2 : in1;
    float* out = blockIdx.z ? out2 : out1;
    __shared__ float tile[32][33];
    int hw0 = blockIdx.x * 32;
    int d0 = blockIdx.y * 32;
    int tx = threadIdx.x, ty = threadIdx.y;  // 32 x 8
#pragma unroll
    for (int j = 0; j < 32; j += 8)
        tile[ty + j][tx] = in[(size_t)(d0 + ty + j) * HWC + hw0 + tx];
    __syncthreads();
#pragma unroll
    for (int j = 0; j < 32; j += 8)
        out[(size_t)(hw0 + ty + j) * DD + d0 + tx] = tile[tx][ty + j];
}

// ---------------- sample points + bilinear + normalize + bf16x3 split ------
__device__ __forceinline__ float fetchd(const float* __restrict__ dt, int y, int x, int d)
{
    bool inb = (x >= 0) && (x < 128) && (y >= 0) && (y < 128);
    int yc = y < 0 ? 0 : (y > 127 ? 127 : y);
    int xc = x < 0 ? 0 : (x > 127 ? 127 : x);
    float v = dt[((size_t)(yc * 128 + xc)) * DD + d];
    return inb ? v : 0.0f;
}

__global__ __launch_bounds__(128) void sample_kernel(
    const float* __restrict__ seg1, const float* __restrict__ seg2,
    const float* __restrict__ dt1, const float* __restrict__ dt2,
    float* __restrict__ dd1, float* __restrict__ dd2,
    unsigned short* __restrict__ h1, unsigned short* __restrict__ m1, unsigned short* __restrict__ l1,
    unsigned short* __restrict__ h2, unsigned short* __restrict__ m2, unsigned short* __restrict__ l2,
    int* __restrict__ v1, int* __restrict__ v2)
{
#pragma clang fp contract(off)
    int L = blockIdx.x;
    int img = blockIdx.y;
    const float* seg = img ? seg2 : seg1;
    const float* dt = img ? dt2 : dt1;
    float* dd = img ? dd2 : dd1;
    unsigned short* ph = img ? h2 : h1;
    unsigned short* pmm = img ? m2 : m1;
    unsigned short* plo = img ? l2 : l1;
    int* vv = img ? v2 : v1;

    float p0y = seg[L * 4 + 0], p0x = seg[L * 4 + 1];
    float p1y = seg[L * 4 + 2], p1x = seg[L * 4 + 3];
    float dy = p0y - p1y, dx = p0x - p1x;
    float len = sqrtf(dy * dy + dx * dx);
    float nf = floorf(len / 8.0f);
    nf = fminf(fmaxf(nf, 2.0f), 10.0f);
    int ni = (int)nf;
    float ivy = (p1y - p0y) / (nf - 1.0f);
    float ivx = (p1x - p0x) / (nf - 1.0f);

    int d = threadIdx.x;
    __shared__ float redw[2];

    for (int t = 0; t < SS; ++t) {
        int pt = L * SS + t;
        bool val = t < ni;  // block-uniform
        float outv = 0.0f;
        if (val) {
            float py = p0y + (float)t * ivy;
            float px = p0x + (float)t * ivx;
            float gx = 2.0f * px / 511.0f - 1.0f;
            float gy = 2.0f * py / 511.0f - 1.0f;
            float ix = ((gx + 1.0f) * 128.0f - 1.0f) / 2.0f;
            float iy = ((gy + 1.0f) * 128.0f - 1.0f) / 2.0f;
            float x0f = floorf(ix), y0f = floorf(iy);
            float wx = ix - x0f, wy = iy - y0f;
            int x0 = (int)x0f, y0 = (int)y0f;
            float g00 = fetchd(dt, y0, x0, d);
            float g01 = fetchd(dt, y0, x0 + 1, d);
            float g10 = fetchd(dt, y0 + 1, x0, d);
            float g11 = fetchd(dt, y0 + 1, x0 + 1, d);
            float omwx = 1.0f - wx, omwy = 1.0f - wy;
            float v = g00 * omwy * omwx + g01 * omwy * wx + g10 * wy * omwx + g11 * wy * wx;
            // wave shuffle reduction (6 steps) + one cross-wave combine
            float s = v * v;
#pragma unroll
            for (int m = 1; m < 64; m <<= 1) s += __shfl_xor(s, m);
            if ((d & 63) == 0) redw[d >> 6] = s;
            __syncthreads();
            float nrm = sqrtf(redw[0] + redw[1]);
            outv = v / fmaxf(nrm, 1e-12f);
        }
        dd[(size_t)pt * DD + d] = outv;
        // exact 3-way bf16 split (truncation): outv = h + m + l + O(2^-24 * outv)
        unsigned ub = __float_as_uint(outv);
        unsigned hb = ub & 0xffff0000u;
        float r1 = outv - __uint_as_float(hb);            // exact
        unsigned mb = __float_as_uint(r1) & 0xffff0000u;
        float r2 = r1 - __uint_as_float(mb);              // exact
        unsigned lb = __float_as_uint(r2) & 0xffff0000u;
        // fragment-major layout: [p>>4][k>>3][p&15][k&7]
        int po = ((pt >> 4) << 11) + ((d >> 3) << 7) + ((pt & 15) << 3) + (d & 7);
        ph[po] = (unsigned short)(hb >> 16);
        pmm[po] = (unsigned short)(mb >> 16);
        plo[po] = (unsigned short)(lb >> 16);
        if (d == 0) vv[pt] = val ? 1 : 0;
        __syncthreads();
    }
}

// ---------------- bf16x3 MFMA GEMM, direct global->VGPR fragments ----------------
// scores = D1 . D2^T emulated as hh + hm + mh + hl + lh + mm  (error ~2^-27 rel)
// Register budget is the whole game here (launch_bounds(256,2) -> 256 unified
// regs/wave): B-frags 60 + A-frags 12 (one i-iter, fenced) + acc 100 (AGPR)
// + addressing ~190 < 256. sched_barrier(0) between i-iterations prevents the
// scheduler from hoisting all 5 iterations' A-loads (which caused scratch
// spill = the 66 MB of WRITE_SIZE in rounds 1-2).
__global__ __launch_bounds__(256, 2) void gemm_ls_kernel(
    const unsigned short* __restrict__ ah_, const unsigned short* __restrict__ am_,
    const unsigned short* __restrict__ al_,
    const unsigned short* __restrict__ bh_, const unsigned short* __restrict__ bm_,
    const unsigned short* __restrict__ bl_,
    const int* __restrict__ v1, const int* __restrict__ v2,
    float* __restrict__ ls, float* __restrict__ lsT)
{
    __shared__ __align__(16) float scr[2 * 6464];  // 51.7 KB epilogue scratch
    int tid = threadIdx.x;
    int wave = tid >> 6, lane = tid & 63;
    int wr = wave >> 1, wc = wave & 1;

    // 2-D XCD tiling: XCD x owns an 8(bi) x 16(bj) sub-grid.
    int flat = blockIdx.y * 32 + blockIdx.x;
    int xcd = flat & 7, n = flat >> 3;
    int bi = (xcd >> 1) * 8 + (n >> 4);
    int bj = (xcd & 1) * 16 + (n & 15);

    int fragoff = ((lane >> 4) << 7) + ((lane & 15) << 3);  // ushort units

    f32x4 zz = {0.0f, 0.0f, 0.0f, 0.0f};
    f32x4 acc[5][5];
#pragma unroll
    for (int i = 0; i < 5; ++i)
#pragma unroll
        for (int j = 0; j < 5; ++j) acc[i][j] = zz;

#pragma unroll 1
    for (int ks = 0; ks < 4; ++ks) {
        bf16x8 B0[5], B1[5], B2[5];
#pragma unroll
        for (int j = 0; j < 5; ++j) {
            size_t off = ((size_t)(bj * 10 + wc * 5 + j) << 11) + (ks << 9) + fragoff;
            B0[j] = *(const bf16x8*)(bh_ + off);
            B1[j] = *(const bf16x8*)(bm_ + off);
            B2[j] = *(const bf16x8*)(bl_ + off);
        }
#pragma unroll
        for (int i = 0; i < 5; ++i) {
            size_t aoff = ((size_t)(bi * 10 + wr * 5 + i) << 11) + (ks << 9) + fragoff;
            bf16x8 fh = *(const bf16x8*)(ah_ + aoff);
            bf16x8 fm = *(const bf16x8*)(am_ + aoff);
            bf16x8 fl = *(const bf16x8*)(al_ + aoff);
#pragma unroll
            for (int j = 0; j < 5; ++j) {
                f32x4 t = acc[i][j];
                t = __builtin_amdgcn_mfma_f32_16x16x32_bf16(fh, B0[j], t, 0, 0, 0);
                t = __builtin_amdgcn_mfma_f32_16x16x32_bf16(fh, B1[j], t, 0, 0, 0);
                t = __builtin_amdgcn_mfma_f32_16x16x32_bf16(fm, B0[j], t, 0, 0, 0);
                t = __builtin_amdgcn_mfma_f32_16x16x32_bf16(fh, B2[j], t, 0, 0, 0);
                t = __builtin_amdgcn_mfma_f32_16x16x32_bf16(fl, B0[j], t, 0, 0, 0);
                t = __builtin_amdgcn_mfma_f32_16x16x32_bf16(fm, B1[j], t, 0, 0, 0);
                acc[i][j] = t;
            }
            // fence: keep next i-iteration's A-loads below, containing live range
            __builtin_amdgcn_sched_barrier(0);
        }
    }

    // ---- fused line-score epilogue: two halves (waves wr==0, then wr==1) ----
    for (int half = 0; half < 2; ++half) {
        __syncthreads();
        if (wr == half) {
            float* reg = scr + wc * 6464;  // 64 pairs * 101 floats, per wave
            // scatter C fragments into pair-major layout (pitch 101: odd -> bank-clean reads)
#pragma unroll
            for (int i = 0; i < 5; ++i)
#pragma unroll
                for (int j = 0; j < 5; ++j)
#pragma unroll
                    for (int r = 0; r < 4; ++r) {
                        int row = i * 16 + ((lane >> 4) << 2) + r;  // 0..79 (C: row=(l>>4)*4+reg)
                        int col = j * 16 + (lane & 15);             // 0..79 (C: col=l&15)
                        int pi = row / 10, s = row - pi * 10;
                        int pj = col / 10, t = col - pj * 10;
                        reg[(pi * 8 + pj) * 101 + s * 10 + t] = acc[i][j][r];
                    }
            asm volatile("s_waitcnt lgkmcnt(0)" ::: "memory");
            // one lane owns one 10x10 line-pair (pair index == lane)
            const float* mp = reg + lane * 101;
            int iL = bi * 16 + half * 8 + (lane >> 3);
            int jL = bj * 16 + wc * 8 + (lane & 7);
            int va[10], vb[10];
#pragma unroll
            for (int s = 0; s < 10; ++s) va[s] = v1[iL * 10 + s];
#pragma unroll
            for (int t = 0; t < 10; ++t) vb[t] = v2[jL * 10 + t];
            float cmx[10];
#pragma unroll
            for (int t = 0; t < 10; ++t) cmx[t] = -3.0e38f;
            float sum1 = 0.0f; int c1 = 0;
#pragma unroll
            for (int s = 0; s < 10; ++s) {
                float rmx = -3.0e38f;
#pragma unroll
                for (int t = 0; t < 10; ++t) {
                    float v = (va[s] && vb[t]) ? mp[s * 10 + t] : -1.0f;
                    rmx = fmaxf(rmx, v);
                    cmx[t] = fmaxf(cmx[t], v);
                }
                if (rmx != -1.0f) { sum1 += rmx; c1++; }
            }
            float sum2 = 0.0f; int c2 = 0;
#pragma unroll
            for (int t = 0; t < 10; ++t) {
                if (cmx[t] != -1.0f) { sum2 += cmx[t]; c2++; }
            }
            float out = (sum1 / (float)c1 + sum2 / (float)c2) * 0.5f;
            ls[(size_t)iL * NL + jL] = out;
            lsT[(size_t)jL * NL + iL] = out;
        }
    }
}

// ---------------- top-10: one wave per (line, dir), repeated max-extraction ------
__global__ __launch_bounds__(64) void topk_kernel(
    const float* __restrict__ ls, const float* __restrict__ lsT, int* __restrict__ topk)
{
    int i = blockIdx.x;
    int dir = blockIdx.y;
    int lane = threadIdx.x;
    const float* src = dir ? &lsT[(size_t)i * NL] : &ls[(size_t)i * NL];

    float v[8];
#pragma unroll
    for (int it = 0; it < 8; ++it) v[it] = src[it * 64 + lane];
    int* outp = &topk[(size_t)(dir * NL + i) * 10];

    for (int p = 9; p >= 0; --p) {
        float bv = -3.0e38f;
        int bi = -1;
#pragma unroll
        for (int it = 0; it < 8; ++it) {
            int j = it * 64 + lane;
            bool better = (v[it] > bv) || (v[it] == bv && j > bi);
            if (better) { bv = v[it]; bi = j; }
        }
#pragma unroll
        for (int m = 1; m < 64; m <<= 1) {
            float ov = __shfl_xor(bv, m);
            int oi = __shfl_xor(bi, m);
            bool better = (ov > bv) || (ov == bv && oi > bi);
            if (better) { bv = ov; bi = oi; }
        }
        if ((bi & 63) == lane) v[bi >> 6] = -3.0e38f;
        if (lane == 0) outp[p] = bi;
    }
}

// ---------------- Needleman-Wunsch on 10x10 blocks of top-10 candidates ----------
__global__ __launch_bounds__(128) void nw_kernel(
    const float* __restrict__ d1, const float* __restrict__ d2,
    const int* __restrict__ v1, const int* __restrict__ v2,
    const int* __restrict__ topk, float* __restrict__ nwout)
{
    int L = blockIdx.x;
    int dir = blockIdx.y;
    const float* Ad = dir ? d2 : d1;
    const float* Bd = dir ? d1 : d2;
    const int* vA = dir ? v2 : v1;
    const int* vB = dir ? v1 : v2;
    const int* tk = topk + (size_t)(dir * NL + L) * 10;

    __shared__ float Asl[10 * 132];
    __shared__ float Bsl[10 * 132];
    __shared__ float M[10][110];  // [cand][s*11+t]
    __shared__ int vam[10];

    int tid = threadIdx.x;
#pragma unroll
    for (int it = 0; it < 10; ++it) {
        int idx = tid + it * 128;
        int row = idx >> 7, col = idx & 127;
        Asl[row * 132 + col] = Ad[((size_t)L * 10 + row) * DD + col];
    }
    if (tid < 10) vam[tid] = vA[L * 10 + tid];

    for (int c = 0; c < 10; ++c) {
        int j = tk[c];
        __syncthreads();
#pragma unroll
        for (int it = 0; it < 10; ++it) {
            int idx = tid + it * 128;
            int row = idx >> 7, col = idx & 127;
            Bsl[row * 132 + col] = Bd[((size_t)j * 10 + row) * DD + col];
        }
        __syncthreads();
        if (tid < 100) {
            int s = tid / 10, t = tid - s * 10;
            const float4* ap = (const float4*)&Asl[s * 132];
            const float4* bp = (const float4*)&Bsl[t * 132];
            float acc = 0.0f;
#pragma unroll
            for (int k = 0; k < 32; ++k) {
                float4 a = ap[k], b = bp[k];
                acc = fmaf(a.x, b.x, acc);
                acc = fmaf(a.y, b.y, acc);
                acc = fmaf(a.z, b.z, acc);
                acc = fmaf(a.w, b.w, acc);
            }
            int ok = vam[s] && vB[j * 10 + t];
            M[c][s * 11 + t] = ok ? acc : -1.0f;
        }
    }
    __syncthreads();

    if (tid < 20) {
        int c = tid % 10, f = tid / 10;
        float prev[11];
#pragma unroll
        for (int p = 0; p < 11; ++p) prev[p] = 0.0f;
#pragma unroll
        for (int s = 0; s < 10; ++s) {
            float oldp = prev[0];
            float run = -3.0e38f;
#pragma unroll
            for (int t = 0; t < 10; ++t) {
                int tt = f ? (9 - t) : t;
                float sc = M[c][s * 11 + tt] - 0.1f;
                float pt1 = prev[t + 1];
                float av = fmaxf(pt1, oldp + sc);
                run = fmaxf(run, av);
                prev[t + 1] = fmaxf(run, 0.0f);
                oldp = pt1;
            }
        }
        nwout[((size_t)(dir * NL + L)) * 20 + f * 10 + c] = prev[10];
    }
}

// ---------------- argmax + mutual check ----------------
__global__ __launch_bounds__(512) void final_kernel(
    const float* __restrict__ nw, const int* __restrict__ topk, int* __restrict__ out)
{
    __shared__ int m1[NL], m2[NL];
    int t = threadIdx.x;
    {
        const float* p = nw + (size_t)t * 20;
        float bb = -3.0e38f; int kk = 0;
        for (int k = 0; k < 20; ++k) {
            float v = p[k];
            if (v > bb) { bb = v; kk = k; }
        }
        m1[t] = topk[(size_t)t * 10 + (kk % 10)];
    }
    {
        const float* p = nw + (size_t)(NL + t) * 20;
        float bb = -3.0e38f; int kk = 0;
        for (int k = 0; k < 20; ++k) {
            float v = p[k];
            if (v > bb) { bb = v; kk = k; }
        }
        m2[t] = topk[(size_t)(NL + t) * 10 + (kk % 10)];
    }
    __syncthreads();
    int mt = m1[t];
    out[t] = (m2[mt] == t) ? mt : -1;
}

extern "C" void kernel_launch(void* const* d_in, const int* in_sizes, int n_in,
                              void* d_out, int out_size, void* d_ws, size_t ws_size,
                              hipStream_t stream)
{
    const float* seg1 = (const float*)d_in[0];
    const float* seg2 = (const float*)d_in[1];
    const float* desc1 = (const float*)d_in[2];
    const float* desc2 = (const float*)d_in[3];
    int* out = (int*)d_out;

    char* ws = (char*)d_ws;
    size_t off = 0;
    float* dt1 = (float*)(ws + off); off += (size_t)DD * HWC * 4;        // 8 MB
    float* dt2 = (float*)(ws + off); off += (size_t)DD * HWC * 4;        // 8 MB
    float* dd1 = (float*)(ws + off); off += (size_t)NL * SS * DD * 4;    // 2.5 MB
    float* dd2 = (float*)(ws + off); off += (size_t)NL * SS * DD * 4;    // 2.5 MB
    int* v1 = (int*)(ws + off); off += (size_t)NL * SS * 4;
    int* v2 = (int*)(ws + off); off += (size_t)NL * SS * 4;
    float* ls = (float*)(ws + off); off += (size_t)NL * NL * 4;          // 1 MB
    float* lsT = (float*)(ws + off); off += (size_t)NL * NL * 4;         // 1 MB
    int* topk = (int*)(ws + off); off += (size_t)2 * NL * 10 * 4;
    float* nwv = (float*)(ws + off); off += (size_t)2 * NL * 20 * 4;
    size_t PL = (size_t)NL * SS * DD;                                    // 655360 elems
    unsigned short* h1 = (unsigned short*)(ws + off); off += PL * 2;     // 1.25 MB each
    unsigned short* m1 = (unsigned short*)(ws + off); off += PL * 2;
    unsigned short* l1 = (unsigned short*)(ws + off); off += PL * 2;
    unsigned short* h2 = (unsigned short*)(ws + off); off += PL * 2;
    unsigned short* m2 = (unsigned short*)(ws + off); off += PL * 2;
    unsigned short* l2 = (unsigned short*)(ws + off); off += PL * 2;

    transpose_kernel<<<dim3(HWC / 32, DD / 32, 2), dim3(32, 8), 0, stream>>>(
        desc1, desc2, dt1, dt2);
    sample_kernel<<<dim3(NL, 2), 128, 0, stream>>>(
        seg1, seg2, dt1, dt2, dd1, dd2, h1, m1, l1, h2, m2, l2, v1, v2);
    gemm_ls_kernel<<<dim3(32, 32), 256, 0, stream>>>(
        h1, m1, l1, h2, m2, l2, v1, v2, ls, lsT);
    topk_kernel<<<dim3(NL, 2), 64, 0, stream>>>(ls, lsT, topk);
    nw_kernel<<<dim3(NL, 2), 128, 0, stream>>>(dd1, dd2, v1, v2, topk, nwv);
    final_kernel<<<1, 512, 0, stream>>>(nwv, topk, out);
}

// Round 4
// 216.903 us; speedup vs baseline: 1.0932x; 1.0932x over previous
//
#include <hip/hip_runtime.h>
#include <cmath>

#define NL 512
#define SS 10
#define DD 128
#define HWC (128 * 128)

typedef _Float16 f16x8 __attribute__((ext_vector_type(8)));
typedef float f32x4 __attribute__((ext_vector_type(4)));

// ---------------- transpose (D, HW) -> (HW, D), both images ----------------
__global__ __launch_bounds__(256) void transpose_kernel(
    const float* __restrict__ in1, const float* __restrict__ in2,
    float* __restrict__ out1, float* __restrict__ out2)
{
    const float* in = blockIdx.z ? in2 : in1;
    float* out = blockIdx.z ? out2 : out1;
    __shared__ float tile[32][33];
    int hw0 = blockIdx.x * 32;
    int d0 = blockIdx.y * 32;
    int tx = threadIdx.x, ty = threadIdx.y;  // 32 x 8
#pragma unroll
    for (int j = 0; j < 32; j += 8)
        tile[ty + j][tx] = in[(size_t)(d0 + ty + j) * HWC + hw0 + tx];
    __syncthreads();
#pragma unroll
    for (int j = 0; j < 32; j += 8)
        out[(size_t)(hw0 + ty + j) * DD + d0 + tx] = tile[tx][ty + j];
}

// ---------------- sample points + bilinear + normalize + f16x2 split ------
// Scaled split: xs = outv * 256 (exact); h = f16(xs); m = f16(xs - h).
// Residual ~2^-22 * |outv|; the 2^8 pre-scale keeps m out of f16-subnormal
// range so MFMA denormal behavior can't degrade it. GEMM computes 65536 *
// scores; epilogue rescales by 2^-16 (exact).
__device__ __forceinline__ float fetchd(const float* __restrict__ dt, int y, int x, int d)
{
    bool inb = (x >= 0) && (x < 128) && (y >= 0) && (y < 128);
    int yc = y < 0 ? 0 : (y > 127 ? 127 : y);
    int xc = x < 0 ? 0 : (x > 127 ? 127 : x);
    float v = dt[((size_t)(yc * 128 + xc)) * DD + d];
    return inb ? v : 0.0f;
}

__global__ __launch_bounds__(128) void sample_kernel(
    const float* __restrict__ seg1, const float* __restrict__ seg2,
    const float* __restrict__ dt1, const float* __restrict__ dt2,
    float* __restrict__ dd1, float* __restrict__ dd2,
    _Float16* __restrict__ h1, _Float16* __restrict__ m1,
    _Float16* __restrict__ h2, _Float16* __restrict__ m2,
    int* __restrict__ v1, int* __restrict__ v2)
{
#pragma clang fp contract(off)
    int L = blockIdx.x;
    int img = blockIdx.y;
    const float* seg = img ? seg2 : seg1;
    const float* dt = img ? dt2 : dt1;
    float* dd = img ? dd2 : dd1;
    _Float16* ph = img ? h2 : h1;
    _Float16* pm = img ? m2 : m1;
    int* vv = img ? v2 : v1;

    float p0y = seg[L * 4 + 0], p0x = seg[L * 4 + 1];
    float p1y = seg[L * 4 + 2], p1x = seg[L * 4 + 3];
    float dy = p0y - p1y, dx = p0x - p1x;
    float len = sqrtf(dy * dy + dx * dx);
    float nf = floorf(len / 8.0f);
    nf = fminf(fmaxf(nf, 2.0f), 10.0f);
    int ni = (int)nf;
    float ivy = (p1y - p0y) / (nf - 1.0f);
    float ivx = (p1x - p0x) / (nf - 1.0f);

    int d = threadIdx.x;
    __shared__ float redw[2];

    for (int t = 0; t < SS; ++t) {
        int pt = L * SS + t;
        bool val = t < ni;  // block-uniform
        float outv = 0.0f;
        if (val) {
            float py = p0y + (float)t * ivy;
            float px = p0x + (float)t * ivx;
            float gx = 2.0f * px / 511.0f - 1.0f;
            float gy = 2.0f * py / 511.0f - 1.0f;
            float ix = ((gx + 1.0f) * 128.0f - 1.0f) / 2.0f;
            float iy = ((gy + 1.0f) * 128.0f - 1.0f) / 2.0f;
            float x0f = floorf(ix), y0f = floorf(iy);
            float wx = ix - x0f, wy = iy - y0f;
            int x0 = (int)x0f, y0 = (int)y0f;
            float g00 = fetchd(dt, y0, x0, d);
            float g01 = fetchd(dt, y0, x0 + 1, d);
            float g10 = fetchd(dt, y0 + 1, x0, d);
            float g11 = fetchd(dt, y0 + 1, x0 + 1, d);
            float omwx = 1.0f - wx, omwy = 1.0f - wy;
            float v = g00 * omwy * omwx + g01 * omwy * wx + g10 * wy * omwx + g11 * wy * wx;
            // wave shuffle reduction (6 steps) + one cross-wave combine
            float s = v * v;
#pragma unroll
            for (int m = 1; m < 64; m <<= 1) s += __shfl_xor(s, m);
            if ((d & 63) == 0) redw[d >> 6] = s;
            __syncthreads();
            float nrm = sqrtf(redw[0] + redw[1]);
            outv = v / fmaxf(nrm, 1e-12f);
        }
        dd[(size_t)pt * DD + d] = outv;
        // scaled f16x2 split
        float xs = outv * 256.0f;
        _Float16 hh = (_Float16)xs;
        float r1 = xs - (float)hh;          // exact (Sterbenz)
        _Float16 mm = (_Float16)r1;
        // fragment-major layout: [p>>4][k>>3][p&15][k&7]
        int po = ((pt >> 4) << 11) + ((d >> 3) << 7) + ((pt & 15) << 3) + (d & 7);
        ph[po] = hh;
        pm[po] = mm;
        if (d == 0) vv[pt] = val ? 1 : 0;
        __syncthreads();
    }
}

// ---------------- f16x2 MFMA GEMM, direct global->VGPR fragments ----------------
// 65536*scores = D1h.D2h^T + D1h.D2m^T + D1m.D2h^T   (error ~2^-22 rel)
// K-loop live set: B-frags 2x5x4=40 + A-frags 8 + acc 100 + addr ~25 ≈ 175
// unified regs -> fits the (256,2) budget without scratch spill.
__global__ __launch_bounds__(256, 2) void gemm_ls_kernel(
    const _Float16* __restrict__ ah_, const _Float16* __restrict__ am_,
    const _Float16* __restrict__ bh_, const _Float16* __restrict__ bm_,
    const int* __restrict__ v1, const int* __restrict__ v2,
    float* __restrict__ ls, float* __restrict__ lsT)
{
    __shared__ __align__(16) float scr[2 * 6464];  // 51.7 KB epilogue scratch
    int tid = threadIdx.x;
    int wave = tid >> 6, lane = tid & 63;
    int wr = wave >> 1, wc = wave & 1;

    // 2-D XCD tiling: XCD x owns an 8(bi) x 16(bj) sub-grid.
    int flat = blockIdx.y * 32 + blockIdx.x;
    int xcd = flat & 7, n = flat >> 3;
    int bi = (xcd >> 1) * 8 + (n >> 4);
    int bj = (xcd & 1) * 16 + (n & 15);

    int fragoff = ((lane >> 4) << 7) + ((lane & 15) << 3);  // f16 units

    f32x4 zz = {0.0f, 0.0f, 0.0f, 0.0f};
    f32x4 acc[5][5];
#pragma unroll
    for (int i = 0; i < 5; ++i)
#pragma unroll
        for (int j = 0; j < 5; ++j) acc[i][j] = zz;

#pragma unroll 1
    for (int ks = 0; ks < 4; ++ks) {
        f16x8 B0[5], B1[5];
#pragma unroll
        for (int j = 0; j < 5; ++j) {
            size_t off = ((size_t)(bj * 10 + wc * 5 + j) << 11) + (ks << 9) + fragoff;
            B0[j] = *(const f16x8*)(bh_ + off);
            B1[j] = *(const f16x8*)(bm_ + off);
        }
#pragma unroll
        for (int i = 0; i < 5; ++i) {
            size_t aoff = ((size_t)(bi * 10 + wr * 5 + i) << 11) + (ks << 9) + fragoff;
            f16x8 fh = *(const f16x8*)(ah_ + aoff);
            f16x8 fm = *(const f16x8*)(am_ + aoff);
#pragma unroll
            for (int j = 0; j < 5; ++j) {
                f32x4 t = acc[i][j];
                t = __builtin_amdgcn_mfma_f32_16x16x32_f16(fh, B0[j], t, 0, 0, 0);
                t = __builtin_amdgcn_mfma_f32_16x16x32_f16(fh, B1[j], t, 0, 0, 0);
                t = __builtin_amdgcn_mfma_f32_16x16x32_f16(fm, B0[j], t, 0, 0, 0);
                acc[i][j] = t;
            }
        }
    }

    // ---- fused line-score epilogue: two halves (waves wr==0, then wr==1) ----
    const float rescale = 1.0f / 65536.0f;
    for (int half = 0; half < 2; ++half) {
        __syncthreads();
        if (wr == half) {
            float* reg = scr + wc * 6464;  // 64 pairs * 101 floats, per wave
            // scatter C fragments into pair-major layout (pitch 101: odd -> bank-clean reads)
#pragma unroll
            for (int i = 0; i < 5; ++i)
#pragma unroll
                for (int j = 0; j < 5; ++j)
#pragma unroll
                    for (int r = 0; r < 4; ++r) {
                        int row = i * 16 + ((lane >> 4) << 2) + r;  // 0..79 (C: row=(l>>4)*4+reg)
                        int col = j * 16 + (lane & 15);             // 0..79 (C: col=l&15)
                        int pi = row / 10, s = row - pi * 10;
                        int pj = col / 10, t = col - pj * 10;
                        reg[(pi * 8 + pj) * 101 + s * 10 + t] = acc[i][j][r] * rescale;
                    }
            asm volatile("s_waitcnt lgkmcnt(0)" ::: "memory");
            // one lane owns one 10x10 line-pair (pair index == lane)
            const float* mp = reg + lane * 101;
            int iL = bi * 16 + half * 8 + (lane >> 3);
            int jL = bj * 16 + wc * 8 + (lane & 7);
            int va[10], vb[10];
#pragma unroll
            for (int s = 0; s < 10; ++s) va[s] = v1[iL * 10 + s];
#pragma unroll
            for (int t = 0; t < 10; ++t) vb[t] = v2[jL * 10 + t];
            float cmx[10];
#pragma unroll
            for (int t = 0; t < 10; ++t) cmx[t] = -3.0e38f;
            float sum1 = 0.0f; int c1 = 0;
#pragma unroll
            for (int s = 0; s < 10; ++s) {
                float rmx = -3.0e38f;
#pragma unroll
                for (int t = 0; t < 10; ++t) {
                    float v = (va[s] && vb[t]) ? mp[s * 10 + t] : -1.0f;
                    rmx = fmaxf(rmx, v);
                    cmx[t] = fmaxf(cmx[t], v);
                }
                if (rmx != -1.0f) { sum1 += rmx; c1++; }
            }
            float sum2 = 0.0f; int c2 = 0;
#pragma unroll
            for (int t = 0; t < 10; ++t) {
                if (cmx[t] != -1.0f) { sum2 += cmx[t]; c2++; }
            }
            float out = (sum1 / (float)c1 + sum2 / (float)c2) * 0.5f;
            ls[(size_t)iL * NL + jL] = out;
            lsT[(size_t)jL * NL + iL] = out;
        }
    }
}

// ---------------- top-10: one wave per (line, dir), repeated max-extraction ------
__global__ __launch_bounds__(64) void topk_kernel(
    const float* __restrict__ ls, const float* __restrict__ lsT, int* __restrict__ topk)
{
    int i = blockIdx.x;
    int dir = blockIdx.y;
    int lane = threadIdx.x;
    const float* src = dir ? &lsT[(size_t)i * NL] : &ls[(size_t)i * NL];

    float v[8];
#pragma unroll
    for (int it = 0; it < 8; ++it) v[it] = src[it * 64 + lane];
    int* outp = &topk[(size_t)(dir * NL + i) * 10];

    for (int p = 9; p >= 0; --p) {
        float bv = -3.0e38f;
        int bi = -1;
#pragma unroll
        for (int it = 0; it < 8; ++it) {
            int j = it * 64 + lane;
            bool better = (v[it] > bv) || (v[it] == bv && j > bi);
            if (better) { bv = v[it]; bi = j; }
        }
#pragma unroll
        for (int m = 1; m < 64; m <<= 1) {
            float ov = __shfl_xor(bv, m);
            int oi = __shfl_xor(bi, m);
            bool better = (ov > bv) || (ov == bv && oi > bi);
            if (better) { bv = ov; bi = oi; }
        }
        if ((bi & 63) == lane) v[bi >> 6] = -3.0e38f;
        if (lane == 0) outp[p] = bi;
    }
}

// ---------------- Needleman-Wunsch on 10x10 blocks of top-10 candidates ----------
__global__ __launch_bounds__(128) void nw_kernel(
    const float* __restrict__ d1, const float* __restrict__ d2,
    const int* __restrict__ v1, const int* __restrict__ v2,
    const int* __restrict__ topk, float* __restrict__ nwout)
{
    int L = blockIdx.x;
    int dir = blockIdx.y;
    const float* Ad = dir ? d2 : d1;
    const float* Bd = dir ? d1 : d2;
    const int* vA = dir ? v2 : v1;
    const int* vB = dir ? v1 : v2;
    const int* tk = topk + (size_t)(dir * NL + L) * 10;

    __shared__ float Asl[10 * 132];
    __shared__ float Bsl[10 * 132];
    __shared__ float M[10][110];  // [cand][s*11+t]
    __shared__ int vam[10];

    int tid = threadIdx.x;
#pragma unroll
    for (int it = 0; it < 10; ++it) {
        int idx = tid + it * 128;
        int row = idx >> 7, col = idx & 127;
        Asl[row * 132 + col] = Ad[((size_t)L * 10 + row) * DD + col];
    }
    if (tid < 10) vam[tid] = vA[L * 10 + tid];

    for (int c = 0; c < 10; ++c) {
        int j = tk[c];
        __syncthreads();
#pragma unroll
        for (int it = 0; it < 10; ++it) {
            int idx = tid + it * 128;
            int row = idx >> 7, col = idx & 127;
            Bsl[row * 132 + col] = Bd[((size_t)j * 10 + row) * DD + col];
        }
        __syncthreads();
        if (tid < 100) {
            int s = tid / 10, t = tid - s * 10;
            const float4* ap = (const float4*)&Asl[s * 132];
            const float4* bp = (const float4*)&Bsl[t * 132];
            float acc = 0.0f;
#pragma unroll
            for (int k = 0; k < 32; ++k) {
                float4 a = ap[k], b = bp[k];
                acc = fmaf(a.x, b.x, acc);
                acc = fmaf(a.y, b.y, acc);
                acc = fmaf(a.z, b.z, acc);
                acc = fmaf(a.w, b.w, acc);
            }
            int ok = vam[s] && vB[j * 10 + t];
            M[c][s * 11 + t] = ok ? acc : -1.0f;
        }
    }
    __syncthreads();

    if (tid < 20) {
        int c = tid % 10, f = tid / 10;
        float prev[11];
#pragma unroll
        for (int p = 0; p < 11; ++p) prev[p] = 0.0f;
#pragma unroll
        for (int s = 0; s < 10; ++s) {
            float oldp = prev[0];
            float run = -3.0e38f;
#pragma unroll
            for (int t = 0; t < 10; ++t) {
                int tt = f ? (9 - t) : t;
                float sc = M[c][s * 11 + tt] - 0.1f;
                float pt1 = prev[t + 1];
                float av = fmaxf(pt1, oldp + sc);
                run = fmaxf(run, av);
                prev[t + 1] = fmaxf(run, 0.0f);
                oldp = pt1;
            }
        }
        nwout[((size_t)(dir * NL + L)) * 20 + f * 10 + c] = prev[10];
    }
}

// ---------------- argmax + mutual check ----------------
__global__ __launch_bounds__(512) void final_kernel(
    const float* __restrict__ nw, const int* __restrict__ topk, int* __restrict__ out)
{
    __shared__ int m1[NL], m2[NL];
    int t = threadIdx.x;
    {
        const float* p = nw + (size_t)t * 20;
        float bb = -3.0e38f; int kk = 0;
        for (int k = 0; k < 20; ++k) {
            float v = p[k];
            if (v > bb) { bb = v; kk = k; }
        }
        m1[t] = topk[(size_t)t * 10 + (kk % 10)];
    }
    {
        const float* p = nw + (size_t)(NL + t) * 20;
        float bb = -3.0e38f; int kk = 0;
        for (int k = 0; k < 20; ++k) {
            float v = p[k];
            if (v > bb) { bb = v; kk = k; }
        }
        m2[t] = topk[(size_t)(NL + t) * 10 + (kk % 10)];
    }
    __syncthreads();
    int mt = m1[t];
    out[t] = (m2[mt] == t) ? mt : -1;
}

extern "C" void kernel_launch(void* const* d_in, const int* in_sizes, int n_in,
                              void* d_out, int out_size, void* d_ws, size_t ws_size,
                              hipStream_t stream)
{
    const float* seg1 = (const float*)d_in[0];
    const float* seg2 = (const float*)d_in[1];
    const float* desc1 = (const float*)d_in[2];
    const float* desc2 = (const float*)d_in[3];
    int* out = (int*)d_out;

    char* ws = (char*)d_ws;
    size_t off = 0;
    float* dt1 = (float*)(ws + off); off += (size_t)DD * HWC * 4;        // 8 MB
    float* dt2 = (float*)(ws + off); off += (size_t)DD * HWC * 4;        // 8 MB
    float* dd1 = (float*)(ws + off); off += (size_t)NL * SS * DD * 4;    // 2.5 MB
    float* dd2 = (float*)(ws + off); off += (size_t)NL * SS * DD * 4;    // 2.5 MB
    int* v1 = (int*)(ws + off); off += (size_t)NL * SS * 4;
    int* v2 = (int*)(ws + off); off += (size_t)NL * SS * 4;
    float* ls = (float*)(ws + off); off += (size_t)NL * NL * 4;          // 1 MB
    float* lsT = (float*)(ws + off); off += (size_t)NL * NL * 4;         // 1 MB
    int* topk = (int*)(ws + off); off += (size_t)2 * NL * 10 * 4;
    float* nwv = (float*)(ws + off); off += (size_t)2 * NL * 20 * 4;
    size_t PL = (size_t)NL * SS * DD;                                    // 655360 elems
    _Float16* h1 = (_Float16*)(ws + off); off += PL * 2;                 // 1.25 MB each
    _Float16* m1 = (_Float16*)(ws + off); off += PL * 2;
    _Float16* h2 = (_Float16*)(ws + off); off += PL * 2;
    _Float16* m2 = (_Float16*)(ws + off); off += PL * 2;

    transpose_kernel<<<dim3(HWC / 32, DD / 32, 2), dim3(32, 8), 0, stream>>>(
        desc1, desc2, dt1, dt2);
    sample_kernel<<<dim3(NL, 2), 128, 0, stream>>>(
        seg1, seg2, dt1, dt2, dd1, dd2, h1, m1, h2, m2, v1, v2);
    gemm_ls_kernel<<<dim3(32, 32), 256, 0, stream>>>(
        h1, m1, h2, m2, v1, v2, ls, lsT);
    topk_kernel<<<dim3(NL, 2), 64, 0, stream>>>(ls, lsT, topk);
    nw_kernel<<<dim3(NL, 2), 128, 0, stream>>>(dd1, dd2, v1, v2, topk, nwv);
    final_kernel<<<1, 512, 0, stream>>>(nwv, topk, out);
}

// Round 5
// 183.814 us; speedup vs baseline: 1.2900x; 1.1800x over previous
//
#include <hip/hip_runtime.h>
#include <cmath>

#define NL 512
#define SS 10
#define DD 128
#define HWC (128 * 128)

typedef _Float16 f16x8 __attribute__((ext_vector_type(8)));
typedef float f32x4 __attribute__((ext_vector_type(4)));

__device__ __forceinline__ void gload_lds16(const void* g, void* l)
{
    __builtin_amdgcn_global_load_lds(
        (__attribute__((address_space(1))) void*)const_cast<void*>(g),
        (__attribute__((address_space(3))) void*)l, 16, 0, 0);
}

// ---------------- transpose (D, HW) -> (HW, D), both images ----------------
__global__ __launch_bounds__(256) void transpose_kernel(
    const float* __restrict__ in1, const float* __restrict__ in2,
    float* __restrict__ out1, float* __restrict__ out2)
{
    const float* in = blockIdx.z ? in2 : in1;
    float* out = blockIdx.z ? out2 : out1;
    __shared__ float tile[32][33];
    int hw0 = blockIdx.x * 32;
    int d0 = blockIdx.y * 32;
    int tx = threadIdx.x, ty = threadIdx.y;  // 32 x 8
#pragma unroll
    for (int j = 0; j < 32; j += 8)
        tile[ty + j][tx] = in[(size_t)(d0 + ty + j) * HWC + hw0 + tx];
    __syncthreads();
#pragma unroll
    for (int j = 0; j < 32; j += 8)
        out[(size_t)(hw0 + ty + j) * DD + d0 + tx] = tile[tx][ty + j];
}

// ---------------- sample points + bilinear + normalize + f16x2 split ------
// 256 threads: two points per iteration (group g = tid>>7), 5 serial rounds.
// Scaled split: xs = outv * 256 (exact); h = f16(xs); m = f16(xs - h).
__device__ __forceinline__ float fetchd(const float* __restrict__ dt, int y, int x, int d)
{
    bool inb = (x >= 0) && (x < 128) && (y >= 0) && (y < 128);
    int yc = y < 0 ? 0 : (y > 127 ? 127 : y);
    int xc = x < 0 ? 0 : (x > 127 ? 127 : x);
    float v = dt[((size_t)(yc * 128 + xc)) * DD + d];
    return inb ? v : 0.0f;
}

__global__ __launch_bounds__(256) void sample_kernel(
    const float* __restrict__ seg1, const float* __restrict__ seg2,
    const float* __restrict__ dt1, const float* __restrict__ dt2,
    float* __restrict__ dd1, float* __restrict__ dd2,
    _Float16* __restrict__ h1, _Float16* __restrict__ m1,
    _Float16* __restrict__ h2, _Float16* __restrict__ m2,
    int* __restrict__ v1, int* __restrict__ v2)
{
#pragma clang fp contract(off)
    int L = blockIdx.x;
    int img = blockIdx.y;
    const float* seg = img ? seg2 : seg1;
    const float* dt = img ? dt2 : dt1;
    float* dd = img ? dd2 : dd1;
    _Float16* ph = img ? h2 : h1;
    _Float16* pm = img ? m2 : m1;
    int* vv = img ? v2 : v1;

    float p0y = seg[L * 4 + 0], p0x = seg[L * 4 + 1];
    float p1y = seg[L * 4 + 2], p1x = seg[L * 4 + 3];
    float dy = p0y - p1y, dx = p0x - p1x;
    float len = sqrtf(dy * dy + dx * dx);
    float nf = floorf(len / 8.0f);
    nf = fminf(fmaxf(nf, 2.0f), 10.0f);
    int ni = (int)nf;
    float ivy = (p1y - p0y) / (nf - 1.0f);
    float ivx = (p1x - p0x) / (nf - 1.0f);

    int tid = threadIdx.x;
    int g = tid >> 7;        // point-group 0/1
    int d = tid & 127;       // descriptor dim
    __shared__ float redw[4];

    for (int it = 0; it < 5; ++it) {
        int t = it * 2 + g;
        int pt = L * SS + t;
        bool val = t < ni;   // group-uniform
        float v = 0.0f, s = 0.0f;
        if (val) {
            float py = p0y + (float)t * ivy;
            float px = p0x + (float)t * ivx;
            float gx = 2.0f * px / 511.0f - 1.0f;
            float gy = 2.0f * py / 511.0f - 1.0f;
            float ix = ((gx + 1.0f) * 128.0f - 1.0f) / 2.0f;
            float iy = ((gy + 1.0f) * 128.0f - 1.0f) / 2.0f;
            float x0f = floorf(ix), y0f = floorf(iy);
            float wx = ix - x0f, wy = iy - y0f;
            int x0 = (int)x0f, y0 = (int)y0f;
            float g00 = fetchd(dt, y0, x0, d);
            float g01 = fetchd(dt, y0, x0 + 1, d);
            float g10 = fetchd(dt, y0 + 1, x0, d);
            float g11 = fetchd(dt, y0 + 1, x0 + 1, d);
            float omwx = 1.0f - wx, omwy = 1.0f - wy;
            v = g00 * omwy * omwx + g01 * omwy * wx + g10 * wy * omwx + g11 * wy * wx;
            s = v * v;
        }
#pragma unroll
        for (int m = 1; m < 64; m <<= 1) s += __shfl_xor(s, m);
        if ((tid & 63) == 0) redw[tid >> 6] = s;
        __syncthreads();
        float outv = 0.0f;
        if (val) {
            float nrm = sqrtf(redw[2 * g] + redw[2 * g + 1]);
            outv = v / fmaxf(nrm, 1e-12f);
        }
        dd[(size_t)pt * DD + d] = outv;
        // scaled f16x2 split
        float xs = outv * 256.0f;
        _Float16 hh = (_Float16)xs;
        float r1 = xs - (float)hh;          // exact
        _Float16 mm = (_Float16)r1;
        // fragment-major layout: [p>>4][k>>3][p&15][k&7]
        int po = ((pt >> 4) << 11) + ((d >> 3) << 7) + ((pt & 15) << 3) + (d & 7);
        ph[po] = hh;
        pm[po] = mm;
        if (d == 0) vv[pt] = val ? 1 : 0;
        __syncthreads();
    }
}

// ---------------- f16x2 MFMA GEMM: LDS double-buffered ks-chunks ----------------
// 65536*scores = D1h.D2h^T + D1h.D2m^T + D1m.D2h^T   (error ~2^-22 rel)
// Per ks: 40 KB tile (A+B, both planes) = 40 x 1KB global_load_lds chunks,
// 10 per wave. K-loop: {issue next stage -> vmcnt(10) -> s_barrier ->
// ds_read+MFMA -> s_barrier}; DMAs for ks+1 stay in flight across compute
// (counted vmcnt, never drained mid-loop -- raw s_barrier, not __syncthreads).
__device__ __forceinline__ void stage_ks(
    const _Float16* __restrict__ ah, const _Float16* __restrict__ am,
    const _Float16* __restrict__ bh, const _Float16* __restrict__ bm,
    int bi, int bj, int ks, int wave, int lane, char* dst)
{
#pragma unroll
    for (int c = 0; c < 10; ++c) {
        int chunk = wave * 10 + c;            // 0..39
        int side = chunk >= 20;
        int rem = side ? chunk - 20 : chunk;
        int plane = rem >= 10;
        int pb = plane ? rem - 10 : rem;
        const _Float16* base = side ? (plane ? bm : bh) : (plane ? am : ah);
        size_t off = ((size_t)((side ? bj : bi) * 10 + pb) << 11) + (ks << 9) + (lane << 3);
        gload_lds16(base + off, dst + (chunk << 10));
    }
}

__global__ __launch_bounds__(256, 2) void gemm_ls_kernel(
    const _Float16* __restrict__ ah_, const _Float16* __restrict__ am_,
    const _Float16* __restrict__ bh_, const _Float16* __restrict__ bm_,
    const int* __restrict__ v1, const int* __restrict__ v2,
    float* __restrict__ ls, float* __restrict__ lsT)
{
    __shared__ __align__(16) char smem[81920];  // 2 x 40KB staging; epilogue overlays
    int tid = threadIdx.x;
    int wave = tid >> 6, lane = tid & 63;
    int wr = wave >> 1, wc = wave & 1;

    // 2-D XCD tiling: XCD x owns an 8(bi) x 16(bj) sub-grid.
    int flat = blockIdx.y * 32 + blockIdx.x;
    int xcd = flat & 7, n = flat >> 3;
    int bi = (xcd >> 1) * 8 + (n >> 4);
    int bj = (xcd & 1) * 16 + (n & 15);

    int fro = ((lane >> 4) << 8) + ((lane & 15) << 4);  // byte offset inside a chunk

    f32x4 zz = {0.0f, 0.0f, 0.0f, 0.0f};
    f32x4 acc[5][5];
#pragma unroll
    for (int i = 0; i < 5; ++i)
#pragma unroll
        for (int j = 0; j < 5; ++j) acc[i][j] = zz;

    stage_ks(ah_, am_, bh_, bm_, bi, bj, 0, wave, lane, smem);  // prologue

#pragma unroll 1
    for (int ks = 0; ks < 4; ++ks) {
        char* buf = smem + ((ks & 1) ? 40960 : 0);
        if (ks < 3) {
            stage_ks(ah_, am_, bh_, bm_, bi, bj, ks + 1, wave, lane,
                     smem + (((ks + 1) & 1) ? 40960 : 0));
            asm volatile("s_waitcnt vmcnt(10)" ::: "memory");
        } else {
            asm volatile("s_waitcnt vmcnt(0)" ::: "memory");
        }
        __builtin_amdgcn_sched_barrier(0);
        __builtin_amdgcn_s_barrier();
        __builtin_amdgcn_sched_barrier(0);

        f16x8 B0[5], B1[5];
#pragma unroll
        for (int j = 0; j < 5; ++j) {
            int pb = wc * 5 + j;
            B0[j] = *(const f16x8*)(buf + ((20 + pb) << 10) + fro);
            B1[j] = *(const f16x8*)(buf + ((30 + pb) << 10) + fro);
        }
#pragma unroll
        for (int i = 0; i < 5; ++i) {
            int pb = wr * 5 + i;
            f16x8 fh = *(const f16x8*)(buf + (pb << 10) + fro);
            f16x8 fm = *(const f16x8*)(buf + ((10 + pb) << 10) + fro);
#pragma unroll
            for (int j = 0; j < 5; ++j) {
                f32x4 t = acc[i][j];
                t = __builtin_amdgcn_mfma_f32_16x16x32_f16(fh, B0[j], t, 0, 0, 0);
                t = __builtin_amdgcn_mfma_f32_16x16x32_f16(fh, B1[j], t, 0, 0, 0);
                t = __builtin_amdgcn_mfma_f32_16x16x32_f16(fm, B0[j], t, 0, 0, 0);
                acc[i][j] = t;
            }
        }
        __builtin_amdgcn_sched_barrier(0);
        __builtin_amdgcn_s_barrier();
        __builtin_amdgcn_sched_barrier(0);
    }

    // ---- fused line-score epilogue: two halves (waves wr==0, then wr==1) ----
    float* scr = (float*)smem;  // overlays dead staging buffers (51.7 KB < 80 KB)
    const float rescale = 1.0f / 65536.0f;
    for (int half = 0; half < 2; ++half) {
        __syncthreads();
        if (wr == half) {
            float* reg = scr + wc * 6464;  // 64 pairs * 101 floats, per wave
#pragma unroll
            for (int i = 0; i < 5; ++i)
#pragma unroll
                for (int j = 0; j < 5; ++j)
#pragma unroll
                    for (int r = 0; r < 4; ++r) {
                        int row = i * 16 + ((lane >> 4) << 2) + r;  // C: row=(l>>4)*4+reg
                        int col = j * 16 + (lane & 15);             // C: col=l&15
                        int pi = row / 10, s = row - pi * 10;
                        int pj = col / 10, t = col - pj * 10;
                        reg[(pi * 8 + pj) * 101 + s * 10 + t] = acc[i][j][r] * rescale;
                    }
            asm volatile("s_waitcnt lgkmcnt(0)" ::: "memory");
            // one lane owns one 10x10 line-pair (pair index == lane)
            const float* mp = reg + lane * 101;
            int iL = bi * 16 + half * 8 + (lane >> 3);
            int jL = bj * 16 + wc * 8 + (lane & 7);
            int va[10], vb[10];
#pragma unroll
            for (int s = 0; s < 10; ++s) va[s] = v1[iL * 10 + s];
#pragma unroll
            for (int t = 0; t < 10; ++t) vb[t] = v2[jL * 10 + t];
            float cmx[10];
#pragma unroll
            for (int t = 0; t < 10; ++t) cmx[t] = -3.0e38f;
            float sum1 = 0.0f; int c1 = 0;
#pragma unroll
            for (int s = 0; s < 10; ++s) {
                float rmx = -3.0e38f;
#pragma unroll
                for (int t = 0; t < 10; ++t) {
                    float v = (va[s] && vb[t]) ? mp[s * 10 + t] : -1.0f;
                    rmx = fmaxf(rmx, v);
                    cmx[t] = fmaxf(cmx[t], v);
                }
                if (rmx != -1.0f) { sum1 += rmx; c1++; }
            }
            float sum2 = 0.0f; int c2 = 0;
#pragma unroll
            for (int t = 0; t < 10; ++t) {
                if (cmx[t] != -1.0f) { sum2 += cmx[t]; c2++; }
            }
            float out = (sum1 / (float)c1 + sum2 / (float)c2) * 0.5f;
            ls[(size_t)iL * NL + jL] = out;
            lsT[(size_t)jL * NL + iL] = out;
        }
    }
}

// ---------------- top-10: one wave per (line, dir), repeated max-extraction ------
__global__ __launch_bounds__(64) void topk_kernel(
    const float* __restrict__ ls, const float* __restrict__ lsT, int* __restrict__ topk)
{
    int i = blockIdx.x;
    int dir = blockIdx.y;
    int lane = threadIdx.x;
    const float* src = dir ? &lsT[(size_t)i * NL] : &ls[(size_t)i * NL];

    float v[8];
#pragma unroll
    for (int it = 0; it < 8; ++it) v[it] = src[it * 64 + lane];
    int* outp = &topk[(size_t)(dir * NL + i) * 10];

    for (int p = 9; p >= 0; --p) {
        float bv = -3.0e38f;
        int bi = -1;
#pragma unroll
        for (int it = 0; it < 8; ++it) {
            int j = it * 64 + lane;
            bool better = (v[it] > bv) || (v[it] == bv && j > bi);
            if (better) { bv = v[it]; bi = j; }
        }
#pragma unroll
        for (int m = 1; m < 64; m <<= 1) {
            float ov = __shfl_xor(bv, m);
            int oi = __shfl_xor(bi, m);
            bool better = (ov > bv) || (ov == bv && oi > bi);
            if (better) { bv = ov; bi = oi; }
        }
        if ((bi & 63) == lane) v[bi >> 6] = -3.0e38f;
        if (lane == 0) outp[p] = bi;
    }
}

// ---------------- Needleman-Wunsch on 10x10 blocks of top-10 candidates ----------
__global__ __launch_bounds__(128) void nw_kernel(
    const float* __restrict__ d1, const float* __restrict__ d2,
    const int* __restrict__ v1, const int* __restrict__ v2,
    const int* __restrict__ topk, float* __restrict__ nwout)
{
    int L = blockIdx.x;
    int dir = blockIdx.y;
    const float* Ad = dir ? d2 : d1;
    const float* Bd = dir ? d1 : d2;
    const int* vA = dir ? v2 : v1;
    const int* vB = dir ? v1 : v2;
    const int* tk = topk + (size_t)(dir * NL + L) * 10;

    __shared__ float Asl[10 * 132];
    __shared__ float Bsl[10 * 132];
    __shared__ float M[10][110];  // [cand][s*11+t]
    __shared__ int vam[10];

    int tid = threadIdx.x;
#pragma unroll
    for (int it = 0; it < 10; ++it) {
        int idx = tid + it * 128;
        int row = idx >> 7, col = idx & 127;
        Asl[row * 132 + col] = Ad[((size_t)L * 10 + row) * DD + col];
    }
    if (tid < 10) vam[tid] = vA[L * 10 + tid];

    for (int c = 0; c < 10; ++c) {
        int j = tk[c];
        __syncthreads();
#pragma unroll
        for (int it = 0; it < 10; ++it) {
            int idx = tid + it * 128;
            int row = idx >> 7, col = idx & 127;
            Bsl[row * 132 + col] = Bd[((size_t)j * 10 + row) * DD + col];
        }
        __syncthreads();
        if (tid < 100) {
            int s = tid / 10, t = tid - s * 10;
            const float4* ap = (const float4*)&Asl[s * 132];
            const float4* bp = (const float4*)&Bsl[t * 132];
            float acc = 0.0f;
#pragma unroll
            for (int k = 0; k < 32; ++k) {
                float4 a = ap[k], b = bp[k];
                acc = fmaf(a.x, b.x, acc);
                acc = fmaf(a.y, b.y, acc);
                acc = fmaf(a.z, b.z, acc);
                acc = fmaf(a.w, b.w, acc);
            }
            int ok = vam[s] && vB[j * 10 + t];
            M[c][s * 11 + t] = ok ? acc : -1.0f;
        }
    }
    __syncthreads();

    if (tid < 20) {
        int c = tid % 10, f = tid / 10;
        float prev[11];
#pragma unroll
        for (int p = 0; p < 11; ++p) prev[p] = 0.0f;
#pragma unroll
        for (int s = 0; s < 10; ++s) {
            float oldp = prev[0];
            float run = -3.0e38f;
#pragma unroll
            for (int t = 0; t < 10; ++t) {
                int tt = f ? (9 - t) : t;
                float sc = M[c][s * 11 + tt] - 0.1f;
                float pt1 = prev[t + 1];
                float av = fmaxf(pt1, oldp + sc);
                run = fmaxf(run, av);
                prev[t + 1] = fmaxf(run, 0.0f);
                oldp = pt1;
            }
        }
        nwout[((size_t)(dir * NL + L)) * 20 + f * 10 + c] = prev[10];
    }
}

// ---------------- argmax + mutual check ----------------
__global__ __launch_bounds__(512) void final_kernel(
    const float* __restrict__ nw, const int* __restrict__ topk, int* __restrict__ out)
{
    __shared__ int m1[NL], m2[NL];
    int t = threadIdx.x;
    {
        const float* p = nw + (size_t)t * 20;
        float bb = -3.0e38f; int kk = 0;
        for (int k = 0; k < 20; ++k) {
            float v = p[k];
            if (v > bb) { bb = v; kk = k; }
        }
        m1[t] = topk[(size_t)t * 10 + (kk % 10)];
    }
    {
        const float* p = nw + (size_t)(NL + t) * 20;
        float bb = -3.0e38f; int kk = 0;
        for (int k = 0; k < 20; ++k) {
            float v = p[k];
            if (v > bb) { bb = v; kk = k; }
        }
        m2[t] = topk[(size_t)(NL + t) * 10 + (kk % 10)];
    }
    __syncthreads();
    int mt = m1[t];
    out[t] = (m2[mt] == t) ? mt : -1;
}

extern "C" void kernel_launch(void* const* d_in, const int* in_sizes, int n_in,
                              void* d_out, int out_size, void* d_ws, size_t ws_size,
                              hipStream_t stream)
{
    const float* seg1 = (const float*)d_in[0];
    const float* seg2 = (const float*)d_in[1];
    const float* desc1 = (const float*)d_in[2];
    const float* desc2 = (const float*)d_in[3];
    int* out = (int*)d_out;

    char* ws = (char*)d_ws;
    size_t off = 0;
    float* dt1 = (float*)(ws + off); off += (size_t)DD * HWC * 4;        // 8 MB
    float* dt2 = (float*)(ws + off); off += (size_t)DD * HWC * 4;        // 8 MB
    float* dd1 = (float*)(ws + off); off += (size_t)NL * SS * DD * 4;    // 2.5 MB
    float* dd2 = (float*)(ws + off); off += (size_t)NL * SS * DD * 4;    // 2.5 MB
    int* v1 = (int*)(ws + off); off += (size_t)NL * SS * 4;
    int* v2 = (int*)(ws + off); off += (size_t)NL * SS * 4;
    float* ls = (float*)(ws + off); off += (size_t)NL * NL * 4;          // 1 MB
    float* lsT = (float*)(ws + off); off += (size_t)NL * NL * 4;         // 1 MB
    int* topk = (int*)(ws + off); off += (size_t)2 * NL * 10 * 4;
    float* nwv = (float*)(ws + off); off += (size_t)2 * NL * 20 * 4;
    size_t PL = (size_t)NL * SS * DD;                                    // 655360 elems
    _Float16* h1 = (_Float16*)(ws + off); off += PL * 2;                 // 1.25 MB each
    _Float16* m1 = (_Float16*)(ws + off); off += PL * 2;
    _Float16* h2 = (_Float16*)(ws + off); off += PL * 2;
    _Float16* m2 = (_Float16*)(ws + off); off += PL * 2;

    transpose_kernel<<<dim3(HWC / 32, DD / 32, 2), dim3(32, 8), 0, stream>>>(
        desc1, desc2, dt1, dt2);
    sample_kernel<<<dim3(NL, 2), 256, 0, stream>>>(
        seg1, seg2, dt1, dt2, dd1, dd2, h1, m1, h2, m2, v1, v2);
    gemm_ls_kernel<<<dim3(32, 32), 256, 0, stream>>>(
        h1, m1, h2, m2, v1, v2, ls, lsT);
    topk_kernel<<<dim3(NL, 2), 64, 0, stream>>>(ls, lsT, topk);
    nw_kernel<<<dim3(NL, 2), 128, 0, stream>>>(dd1, dd2, v1, v2, topk, nwv);
    final_kernel<<<1, 512, 0, stream>>>(nwv, topk, out);
}

// Round 6
// 183.715 us; speedup vs baseline: 1.2907x; 1.0005x over previous
//
#include <hip/hip_runtime.h>
#include <cmath>

#define NL 512
#define SS 10
#define DD 128
#define HWC (128 * 128)

typedef _Float16 f16x8 __attribute__((ext_vector_type(8)));
typedef float f32x4 __attribute__((ext_vector_type(4)));

__device__ __forceinline__ void gload_lds16(const void* g, void* l)
{
    __builtin_amdgcn_global_load_lds(
        (__attribute__((address_space(1))) void*)const_cast<void*>(g),
        (__attribute__((address_space(3))) void*)l, 16, 0, 0);
}

// ---------------- transpose (D, HW) -> (HW, D), both images ----------------
__global__ __launch_bounds__(256) void transpose_kernel(
    const float* __restrict__ in1, const float* __restrict__ in2,
    float* __restrict__ out1, float* __restrict__ out2)
{
    const float* in = blockIdx.z ? in2 : in1;
    float* out = blockIdx.z ? out2 : out1;
    __shared__ float tile[32][33];
    int hw0 = blockIdx.x * 32;
    int d0 = blockIdx.y * 32;
    int tx = threadIdx.x, ty = threadIdx.y;  // 32 x 8
#pragma unroll
    for (int j = 0; j < 32; j += 8)
        tile[ty + j][tx] = in[(size_t)(d0 + ty + j) * HWC + hw0 + tx];
    __syncthreads();
#pragma unroll
    for (int j = 0; j < 32; j += 8)
        out[(size_t)(hw0 + ty + j) * DD + d0 + tx] = tile[tx][ty + j];
}

// ---------------- sample points: one wave per point, barrier-free ----------
// 640 threads = 10 waves; wave t owns point t. Lane holds dims d and d+64;
// norm = 6-step shfl_xor reduce (no LDS, no __syncthreads).
// Scaled split: xs = outv * 256 (exact); h = f16(xs); m = f16(xs - h).
__device__ __forceinline__ float fetchd(const float* __restrict__ dt, int y, int x, int d)
{
    bool inb = (x >= 0) && (x < 128) && (y >= 0) && (y < 128);
    int yc = y < 0 ? 0 : (y > 127 ? 127 : y);
    int xc = x < 0 ? 0 : (x > 127 ? 127 : x);
    float v = dt[((size_t)(yc * 128 + xc)) * DD + d];
    return inb ? v : 0.0f;
}

__global__ __launch_bounds__(640) void sample_kernel(
    const float* __restrict__ seg1, const float* __restrict__ seg2,
    const float* __restrict__ dt1, const float* __restrict__ dt2,
    float* __restrict__ dd1, float* __restrict__ dd2,
    _Float16* __restrict__ h1, _Float16* __restrict__ m1,
    _Float16* __restrict__ h2, _Float16* __restrict__ m2,
    int* __restrict__ v1, int* __restrict__ v2)
{
#pragma clang fp contract(off)
    int L = blockIdx.x;
    int img = blockIdx.y;
    const float* seg = img ? seg2 : seg1;
    const float* dt = img ? dt2 : dt1;
    float* dd = img ? dd2 : dd1;
    _Float16* ph = img ? h2 : h1;
    _Float16* pm = img ? m2 : m1;
    int* vv = img ? v2 : v1;

    float p0y = seg[L * 4 + 0], p0x = seg[L * 4 + 1];
    float p1y = seg[L * 4 + 2], p1x = seg[L * 4 + 3];
    float dy = p0y - p1y, dx = p0x - p1x;
    float len = sqrtf(dy * dy + dx * dx);
    float nf = floorf(len / 8.0f);
    nf = fminf(fmaxf(nf, 2.0f), 10.0f);
    int ni = (int)nf;
    float ivy = (p1y - p0y) / (nf - 1.0f);
    float ivx = (p1x - p0x) / (nf - 1.0f);

    int t = threadIdx.x >> 6;    // point index 0..9 (one wave per point)
    int lane = threadIdx.x & 63;
    int pt = L * SS + t;
    bool val = t < ni;           // wave-uniform
    int d0 = lane, d1 = lane + 64;
    float o0 = 0.0f, o1 = 0.0f;
    if (val) {
        float py = p0y + (float)t * ivy;
        float px = p0x + (float)t * ivx;
        float gx = 2.0f * px / 511.0f - 1.0f;
        float gy = 2.0f * py / 511.0f - 1.0f;
        float ix = ((gx + 1.0f) * 128.0f - 1.0f) / 2.0f;
        float iy = ((gy + 1.0f) * 128.0f - 1.0f) / 2.0f;
        float x0f = floorf(ix), y0f = floorf(iy);
        float wx = ix - x0f, wy = iy - y0f;
        int x0 = (int)x0f, y0 = (int)y0f;
        float a00 = fetchd(dt, y0, x0, d0),         b00 = fetchd(dt, y0, x0, d1);
        float a01 = fetchd(dt, y0, x0 + 1, d0),     b01 = fetchd(dt, y0, x0 + 1, d1);
        float a10 = fetchd(dt, y0 + 1, x0, d0),     b10 = fetchd(dt, y0 + 1, x0, d1);
        float a11 = fetchd(dt, y0 + 1, x0 + 1, d0), b11 = fetchd(dt, y0 + 1, x0 + 1, d1);
        float omwx = 1.0f - wx, omwy = 1.0f - wy;
        float va = a00 * omwy * omwx + a01 * omwy * wx + a10 * wy * omwx + a11 * wy * wx;
        float vb = b00 * omwy * omwx + b01 * omwy * wx + b10 * wy * omwx + b11 * wy * wx;
        float s = va * va + vb * vb;
#pragma unroll
        for (int m = 1; m < 64; m <<= 1) s += __shfl_xor(s, m);
        float nrm = sqrtf(s);
        float inv = 1.0f;  // keep exact division semantics
        o0 = va / fmaxf(nrm, 1e-12f);
        o1 = vb / fmaxf(nrm, 1e-12f);
        (void)inv;
    }
    dd[(size_t)pt * DD + d0] = o0;
    dd[(size_t)pt * DD + d1] = o1;
    float xs0 = o0 * 256.0f;
    _Float16 hh0 = (_Float16)xs0;
    _Float16 mm0 = (_Float16)(xs0 - (float)hh0);
    float xs1 = o1 * 256.0f;
    _Float16 hh1 = (_Float16)xs1;
    _Float16 mm1 = (_Float16)(xs1 - (float)hh1);
    // fragment-major layout: [p>>4][k>>3][p&15][k&7]
    int po0 = ((pt >> 4) << 11) + ((d0 >> 3) << 7) + ((pt & 15) << 3) + (d0 & 7);
    int po1 = ((pt >> 4) << 11) + ((d1 >> 3) << 7) + ((pt & 15) << 3) + (d1 & 7);
    ph[po0] = hh0; pm[po0] = mm0;
    ph[po1] = hh1; pm[po1] = mm1;
    if (lane == 0) vv[pt] = val ? 1 : 0;
}

// ---------------- f16x2 MFMA GEMM: LDS double-buffered ks-chunks ----------------
// (unchanged from round 5 -- serves as the A/B control for this round)
__device__ __forceinline__ void stage_ks(
    const _Float16* __restrict__ ah, const _Float16* __restrict__ am,
    const _Float16* __restrict__ bh, const _Float16* __restrict__ bm,
    int bi, int bj, int ks, int wave, int lane, char* dst)
{
#pragma unroll
    for (int c = 0; c < 10; ++c) {
        int chunk = wave * 10 + c;            // 0..39
        int side = chunk >= 20;
        int rem = side ? chunk - 20 : chunk;
        int plane = rem >= 10;
        int pb = plane ? rem - 10 : rem;
        const _Float16* base = side ? (plane ? bm : bh) : (plane ? am : ah);
        size_t off = ((size_t)((side ? bj : bi) * 10 + pb) << 11) + (ks << 9) + (lane << 3);
        gload_lds16(base + off, dst + (chunk << 10));
    }
}

__global__ __launch_bounds__(256, 2) void gemm_ls_kernel(
    const _Float16* __restrict__ ah_, const _Float16* __restrict__ am_,
    const _Float16* __restrict__ bh_, const _Float16* __restrict__ bm_,
    const int* __restrict__ v1, const int* __restrict__ v2,
    float* __restrict__ ls, float* __restrict__ lsT)
{
    __shared__ __align__(16) char smem[81920];  // 2 x 40KB staging; epilogue overlays
    int tid = threadIdx.x;
    int wave = tid >> 6, lane = tid & 63;
    int wr = wave >> 1, wc = wave & 1;

    // 2-D XCD tiling: XCD x owns an 8(bi) x 16(bj) sub-grid.
    int flat = blockIdx.y * 32 + blockIdx.x;
    int xcd = flat & 7, n = flat >> 3;
    int bi = (xcd >> 1) * 8 + (n >> 4);
    int bj = (xcd & 1) * 16 + (n & 15);

    int fro = ((lane >> 4) << 8) + ((lane & 15) << 4);  // byte offset inside a chunk

    f32x4 zz = {0.0f, 0.0f, 0.0f, 0.0f};
    f32x4 acc[5][5];
#pragma unroll
    for (int i = 0; i < 5; ++i)
#pragma unroll
        for (int j = 0; j < 5; ++j) acc[i][j] = zz;

    stage_ks(ah_, am_, bh_, bm_, bi, bj, 0, wave, lane, smem);  // prologue

#pragma unroll 1
    for (int ks = 0; ks < 4; ++ks) {
        char* buf = smem + ((ks & 1) ? 40960 : 0);
        if (ks < 3) {
            stage_ks(ah_, am_, bh_, bm_, bi, bj, ks + 1, wave, lane,
                     smem + (((ks + 1) & 1) ? 40960 : 0));
            asm volatile("s_waitcnt vmcnt(10)" ::: "memory");
        } else {
            asm volatile("s_waitcnt vmcnt(0)" ::: "memory");
        }
        __builtin_amdgcn_sched_barrier(0);
        __builtin_amdgcn_s_barrier();
        __builtin_amdgcn_sched_barrier(0);

        f16x8 B0[5], B1[5];
#pragma unroll
        for (int j = 0; j < 5; ++j) {
            int pb = wc * 5 + j;
            B0[j] = *(const f16x8*)(buf + ((20 + pb) << 10) + fro);
            B1[j] = *(const f16x8*)(buf + ((30 + pb) << 10) + fro);
        }
#pragma unroll
        for (int i = 0; i < 5; ++i) {
            int pb = wr * 5 + i;
            f16x8 fh = *(const f16x8*)(buf + (pb << 10) + fro);
            f16x8 fm = *(const f16x8*)(buf + ((10 + pb) << 10) + fro);
#pragma unroll
            for (int j = 0; j < 5; ++j) {
                f32x4 t = acc[i][j];
                t = __builtin_amdgcn_mfma_f32_16x16x32_f16(fh, B0[j], t, 0, 0, 0);
                t = __builtin_amdgcn_mfma_f32_16x16x32_f16(fh, B1[j], t, 0, 0, 0);
                t = __builtin_amdgcn_mfma_f32_16x16x32_f16(fm, B0[j], t, 0, 0, 0);
                acc[i][j] = t;
            }
        }
        __builtin_amdgcn_sched_barrier(0);
        __builtin_amdgcn_s_barrier();
        __builtin_amdgcn_sched_barrier(0);
    }

    // ---- fused line-score epilogue: two halves (waves wr==0, then wr==1) ----
    float* scr = (float*)smem;  // overlays dead staging buffers
    const float rescale = 1.0f / 65536.0f;
    for (int half = 0; half < 2; ++half) {
        __syncthreads();
        if (wr == half) {
            float* reg = scr + wc * 6464;  // 64 pairs * 101 floats, per wave
#pragma unroll
            for (int i = 0; i < 5; ++i)
#pragma unroll
                for (int j = 0; j < 5; ++j)
#pragma unroll
                    for (int r = 0; r < 4; ++r) {
                        int row = i * 16 + ((lane >> 4) << 2) + r;  // C: row=(l>>4)*4+reg
                        int col = j * 16 + (lane & 15);             // C: col=l&15
                        int pi = row / 10, s = row - pi * 10;
                        int pj = col / 10, t = col - pj * 10;
                        reg[(pi * 8 + pj) * 101 + s * 10 + t] = acc[i][j][r] * rescale;
                    }
            asm volatile("s_waitcnt lgkmcnt(0)" ::: "memory");
            // one lane owns one 10x10 line-pair (pair index == lane)
            const float* mp = reg + lane * 101;
            int iL = bi * 16 + half * 8 + (lane >> 3);
            int jL = bj * 16 + wc * 8 + (lane & 7);
            int va[10], vb[10];
#pragma unroll
            for (int s = 0; s < 10; ++s) va[s] = v1[iL * 10 + s];
#pragma unroll
            for (int t = 0; t < 10; ++t) vb[t] = v2[jL * 10 + t];
            float cmx[10];
#pragma unroll
            for (int t = 0; t < 10; ++t) cmx[t] = -3.0e38f;
            float sum1 = 0.0f; int c1 = 0;
#pragma unroll
            for (int s = 0; s < 10; ++s) {
                float rmx = -3.0e38f;
#pragma unroll
                for (int t = 0; t < 10; ++t) {
                    float v = (va[s] && vb[t]) ? mp[s * 10 + t] : -1.0f;
                    rmx = fmaxf(rmx, v);
                    cmx[t] = fmaxf(cmx[t], v);
                }
                if (rmx != -1.0f) { sum1 += rmx; c1++; }
            }
            float sum2 = 0.0f; int c2 = 0;
#pragma unroll
            for (int t = 0; t < 10; ++t) {
                if (cmx[t] != -1.0f) { sum2 += cmx[t]; c2++; }
            }
            float out = (sum1 / (float)c1 + sum2 / (float)c2) * 0.5f;
            ls[(size_t)iL * NL + jL] = out;
            lsT[(size_t)jL * NL + iL] = out;
        }
    }
}

// ---------------- top-10: one wave per (line, dir), repeated max-extraction ------
__global__ __launch_bounds__(64) void topk_kernel(
    const float* __restrict__ ls, const float* __restrict__ lsT, int* __restrict__ topk)
{
    int i = blockIdx.x;
    int dir = blockIdx.y;
    int lane = threadIdx.x;
    const float* src = dir ? &lsT[(size_t)i * NL] : &ls[(size_t)i * NL];

    float v[8];
#pragma unroll
    for (int it = 0; it < 8; ++it) v[it] = src[it * 64 + lane];
    int* outp = &topk[(size_t)(dir * NL + i) * 10];

    for (int p = 9; p >= 0; --p) {
        float bv = -3.0e38f;
        int bi = -1;
#pragma unroll
        for (int it = 0; it < 8; ++it) {
            int j = it * 64 + lane;
            bool better = (v[it] > bv) || (v[it] == bv && j > bi);
            if (better) { bv = v[it]; bi = j; }
        }
#pragma unroll
        for (int m = 1; m < 64; m <<= 1) {
            float ov = __shfl_xor(bv, m);
            int oi = __shfl_xor(bi, m);
            bool better = (ov > bv) || (ov == bv && oi > bi);
            if (better) { bv = ov; bi = oi; }
        }
        if ((bi & 63) == lane) v[bi >> 6] = -3.0e38f;
        if (lane == 0) outp[p] = bi;
    }
}

// ---------------- Needleman-Wunsch: stage-once, parallel dots ----------------
// 256 threads. A (1280f) + all 10 candidate B blocks (12800f) staged in one
// pass; 1000 (c,s,t) dots computed in 4 parallel rounds; DP on 20 threads.
// 3 barriers total (was 21). Dot FP order identical to previous version.
__global__ __launch_bounds__(256) void nw_kernel(
    const float* __restrict__ d1, const float* __restrict__ d2,
    const int* __restrict__ v1, const int* __restrict__ v2,
    const int* __restrict__ topk, float* __restrict__ nwout)
{
    int L = blockIdx.x;
    int dir = blockIdx.y;
    const float* Ad = dir ? d2 : d1;
    const float* Bd = dir ? d1 : d2;
    const int* vA = dir ? v2 : v1;
    const int* vB = dir ? v1 : v2;
    const int* tk = topk + (size_t)(dir * NL + L) * 10;

    __shared__ float Asl[10 * 132];       // 5.3 KB
    __shared__ float Bsl[10][1320];       // 52.8 KB
    __shared__ float M[10][110];          // [cand][s*11+t]
    __shared__ int vam[10], tks[10];

    int tid = threadIdx.x;
    if (tid < 10) { vam[tid] = vA[L * 10 + tid]; tks[tid] = tk[tid]; }
#pragma unroll
    for (int it = 0; it < 5; ++it) {
        int idx = tid + it * 256;
        int row = idx >> 7, col = idx & 127;
        Asl[row * 132 + col] = Ad[((size_t)L * 10 + row) * DD + col];
    }
    __syncthreads();
#pragma unroll
    for (int it = 0; it < 50; ++it) {
        int idx = tid + it * 256;
        int c = idx / 1280;
        int rem = idx - c * 1280;
        int row = rem >> 7, col = rem & 127;
        Bsl[c][row * 132 + col] = Bd[((size_t)tks[c] * 10 + row) * DD + col];
    }
    __syncthreads();
#pragma unroll
    for (int it = 0; it < 4; ++it) {
        int w = tid + it * 256;
        if (w < 1000) {
            int c = w / 100;
            int rem = w - c * 100;
            int s = rem / 10, t = rem - s * 10;
            const float4* ap = (const float4*)&Asl[s * 132];
            const float4* bp = (const float4*)&Bsl[c][t * 132];
            float acc = 0.0f;
#pragma unroll
            for (int k = 0; k < 32; ++k) {
                float4 a = ap[k], b = bp[k];
                acc = fmaf(a.x, b.x, acc);
                acc = fmaf(a.y, b.y, acc);
                acc = fmaf(a.z, b.z, acc);
                acc = fmaf(a.w, b.w, acc);
            }
            int ok = vam[s] && vB[tks[c] * 10 + t];
            M[c][s * 11 + t] = ok ? acc : -1.0f;
        }
    }
    __syncthreads();

    if (tid < 20) {
        int c = tid % 10, f = tid / 10;
        float prev[11];
#pragma unroll
        for (int p = 0; p < 11; ++p) prev[p] = 0.0f;
#pragma unroll
        for (int s = 0; s < 10; ++s) {
            float oldp = prev[0];
            float run = -3.0e38f;
#pragma unroll
            for (int t = 0; t < 10; ++t) {
                int tt = f ? (9 - t) : t;
                float sc = M[c][s * 11 + tt] - 0.1f;
                float pt1 = prev[t + 1];
                float av = fmaxf(pt1, oldp + sc);
                run = fmaxf(run, av);
                prev[t + 1] = fmaxf(run, 0.0f);
                oldp = pt1;
            }
        }
        nwout[((size_t)(dir * NL + L)) * 20 + f * 10 + c] = prev[10];
    }
}

// ---------------- argmax + mutual check ----------------
__global__ __launch_bounds__(512) void final_kernel(
    const float* __restrict__ nw, const int* __restrict__ topk, int* __restrict__ out)
{
    __shared__ int m1[NL], m2[NL];
    int t = threadIdx.x;
    {
        const float* p = nw + (size_t)t * 20;
        float bb = -3.0e38f; int kk = 0;
        for (int k = 0; k < 20; ++k) {
            float v = p[k];
            if (v > bb) { bb = v; kk = k; }
        }
        m1[t] = topk[(size_t)t * 10 + (kk % 10)];
    }
    {
        const float* p = nw + (size_t)(NL + t) * 20;
        float bb = -3.0e38f; int kk = 0;
        for (int k = 0; k < 20; ++k) {
            float v = p[k];
            if (v > bb) { bb = v; kk = k; }
        }
        m2[t] = topk[(size_t)(NL + t) * 10 + (kk % 10)];
    }
    __syncthreads();
    int mt = m1[t];
    out[t] = (m2[mt] == t) ? mt : -1;
}

extern "C" void kernel_launch(void* const* d_in, const int* in_sizes, int n_in,
                              void* d_out, int out_size, void* d_ws, size_t ws_size,
                              hipStream_t stream)
{
    const float* seg1 = (const float*)d_in[0];
    const float* seg2 = (const float*)d_in[1];
    const float* desc1 = (const float*)d_in[2];
    const float* desc2 = (const float*)d_in[3];
    int* out = (int*)d_out;

    char* ws = (char*)d_ws;
    size_t off = 0;
    float* dt1 = (float*)(ws + off); off += (size_t)DD * HWC * 4;        // 8 MB
    float* dt2 = (float*)(ws + off); off += (size_t)DD * HWC * 4;        // 8 MB
    float* dd1 = (float*)(ws + off); off += (size_t)NL * SS * DD * 4;    // 2.5 MB
    float* dd2 = (float*)(ws + off); off += (size_t)NL * SS * DD * 4;    // 2.5 MB
    int* v1 = (int*)(ws + off); off += (size_t)NL * SS * 4;
    int* v2 = (int*)(ws + off); off += (size_t)NL * SS * 4;
    float* ls = (float*)(ws + off); off += (size_t)NL * NL * 4;          // 1 MB
    float* lsT = (float*)(ws + off); off += (size_t)NL * NL * 4;         // 1 MB
    int* topk = (int*)(ws + off); off += (size_t)2 * NL * 10 * 4;
    float* nwv = (float*)(ws + off); off += (size_t)2 * NL * 20 * 4;
    size_t PL = (size_t)NL * SS * DD;                                    // 655360 elems
    _Float16* h1 = (_Float16*)(ws + off); off += PL * 2;                 // 1.25 MB each
    _Float16* m1 = (_Float16*)(ws + off); off += PL * 2;
    _Float16* h2 = (_Float16*)(ws + off); off += PL * 2;
    _Float16* m2 = (_Float16*)(ws + off); off += PL * 2;

    transpose_kernel<<<dim3(HWC / 32, DD / 32, 2), dim3(32, 8), 0, stream>>>(
        desc1, desc2, dt1, dt2);
    sample_kernel<<<dim3(NL, 2), 640, 0, stream>>>(
        seg1, seg2, dt1, dt2, dd1, dd2, h1, m1, h2, m2, v1, v2);
    gemm_ls_kernel<<<dim3(32, 32), 256, 0, stream>>>(
        h1, m1, h2, m2, v1, v2, ls, lsT);
    topk_kernel<<<dim3(NL, 2), 64, 0, stream>>>(ls, lsT, topk);
    nw_kernel<<<dim3(NL, 2), 256, 0, stream>>>(dd1, dd2, v1, v2, topk, nwv);
    final_kernel<<<1, 512, 0, stream>>>(nwv, topk, out);
}

// Round 7
// 182.157 us; speedup vs baseline: 1.3017x; 1.0086x over previous
//
#include <hip/hip_runtime.h>
#include <cmath>

#define NL 512
#define SS 10
#define DD 128
#define HWC (128 * 128)

typedef _Float16 f16x8 __attribute__((ext_vector_type(8)));
typedef float f32x4 __attribute__((ext_vector_type(4)));

__device__ __forceinline__ void gload_lds16(const void* g, void* l)
{
    __builtin_amdgcn_global_load_lds(
        (__attribute__((address_space(1))) void*)const_cast<void*>(g),
        (__attribute__((address_space(3))) void*)l, 16, 0, 0);
}

// ---------------- transpose (D, HW) -> (HW, D), both images ----------------
__global__ __launch_bounds__(256) void transpose_kernel(
    const float* __restrict__ in1, const float* __restrict__ in2,
    float* __restrict__ out1, float* __restrict__ out2)
{
    const float* in = blockIdx.z ? in2 : in1;
    float* out = blockIdx.z ? out2 : out1;
    __shared__ float tile[32][33];
    int hw0 = blockIdx.x * 32;
    int d0 = blockIdx.y * 32;
    int tx = threadIdx.x, ty = threadIdx.y;  // 32 x 8
#pragma unroll
    for (int j = 0; j < 32; j += 8)
        tile[ty + j][tx] = in[(size_t)(d0 + ty + j) * HWC + hw0 + tx];
    __syncthreads();
#pragma unroll
    for (int j = 0; j < 32; j += 8)
        out[(size_t)(hw0 + ty + j) * DD + d0 + tx] = tile[tx][ty + j];
}

// ---------------- sample points: one wave per point, barrier-free ----------
__device__ __forceinline__ float fetchd(const float* __restrict__ dt, int y, int x, int d)
{
    bool inb = (x >= 0) && (x < 128) && (y >= 0) && (y < 128);
    int yc = y < 0 ? 0 : (y > 127 ? 127 : y);
    int xc = x < 0 ? 0 : (x > 127 ? 127 : x);
    float v = dt[((size_t)(yc * 128 + xc)) * DD + d];
    return inb ? v : 0.0f;
}

__global__ __launch_bounds__(640) void sample_kernel(
    const float* __restrict__ seg1, const float* __restrict__ seg2,
    const float* __restrict__ dt1, const float* __restrict__ dt2,
    float* __restrict__ dd1, float* __restrict__ dd2,
    _Float16* __restrict__ h1, _Float16* __restrict__ m1,
    _Float16* __restrict__ h2, _Float16* __restrict__ m2,
    int* __restrict__ v1, int* __restrict__ v2)
{
#pragma clang fp contract(off)
    int L = blockIdx.x;
    int img = blockIdx.y;
    const float* seg = img ? seg2 : seg1;
    const float* dt = img ? dt2 : dt1;
    float* dd = img ? dd2 : dd1;
    _Float16* ph = img ? h2 : h1;
    _Float16* pm = img ? m2 : m1;
    int* vv = img ? v2 : v1;

    float p0y = seg[L * 4 + 0], p0x = seg[L * 4 + 1];
    float p1y = seg[L * 4 + 2], p1x = seg[L * 4 + 3];
    float dy = p0y - p1y, dx = p0x - p1x;
    float len = sqrtf(dy * dy + dx * dx);
    float nf = floorf(len / 8.0f);
    nf = fminf(fmaxf(nf, 2.0f), 10.0f);
    int ni = (int)nf;
    float ivy = (p1y - p0y) / (nf - 1.0f);
    float ivx = (p1x - p0x) / (nf - 1.0f);

    int t = threadIdx.x >> 6;    // point index 0..9 (one wave per point)
    int lane = threadIdx.x & 63;
    int pt = L * SS + t;
    bool val = t < ni;           // wave-uniform
    int d0 = lane, d1 = lane + 64;
    float o0 = 0.0f, o1 = 0.0f;
    if (val) {
        float py = p0y + (float)t * ivy;
        float px = p0x + (float)t * ivx;
        float gx = 2.0f * px / 511.0f - 1.0f;
        float gy = 2.0f * py / 511.0f - 1.0f;
        float ix = ((gx + 1.0f) * 128.0f - 1.0f) / 2.0f;
        float iy = ((gy + 1.0f) * 128.0f - 1.0f) / 2.0f;
        float x0f = floorf(ix), y0f = floorf(iy);
        float wx = ix - x0f, wy = iy - y0f;
        int x0 = (int)x0f, y0 = (int)y0f;
        float a00 = fetchd(dt, y0, x0, d0),         b00 = fetchd(dt, y0, x0, d1);
        float a01 = fetchd(dt, y0, x0 + 1, d0),     b01 = fetchd(dt, y0, x0 + 1, d1);
        float a10 = fetchd(dt, y0 + 1, x0, d0),     b10 = fetchd(dt, y0 + 1, x0, d1);
        float a11 = fetchd(dt, y0 + 1, x0 + 1, d0), b11 = fetchd(dt, y0 + 1, x0 + 1, d1);
        float omwx = 1.0f - wx, omwy = 1.0f - wy;
        float va = a00 * omwy * omwx + a01 * omwy * wx + a10 * wy * omwx + a11 * wy * wx;
        float vb = b00 * omwy * omwx + b01 * omwy * wx + b10 * wy * omwx + b11 * wy * wx;
        float s = va * va + vb * vb;
#pragma unroll
        for (int m = 1; m < 64; m <<= 1) s += __shfl_xor(s, m);
        float nrm = sqrtf(s);
        o0 = va / fmaxf(nrm, 1e-12f);
        o1 = vb / fmaxf(nrm, 1e-12f);
    }
    dd[(size_t)pt * DD + d0] = o0;
    dd[(size_t)pt * DD + d1] = o1;
    float xs0 = o0 * 256.0f;
    _Float16 hh0 = (_Float16)xs0;
    _Float16 mm0 = (_Float16)(xs0 - (float)hh0);
    float xs1 = o1 * 256.0f;
    _Float16 hh1 = (_Float16)xs1;
    _Float16 mm1 = (_Float16)(xs1 - (float)hh1);
    // fragment-major layout: [p>>4][k>>3][p&15][k&7]
    int po0 = ((pt >> 4) << 11) + ((d0 >> 3) << 7) + ((pt & 15) << 3) + (d0 & 7);
    int po1 = ((pt >> 4) << 11) + ((d1 >> 3) << 7) + ((pt & 15) << 3) + (d1 & 7);
    ph[po0] = hh0; pm[po0] = mm0;
    ph[po1] = hh1; pm[po1] = mm1;
    if (lane == 0) vv[pt] = val ? 1 : 0;
}

// ---------------- f16x2 MFMA GEMM: 160x320 tile, 8 waves, LDS dbuf ----------
// 65536*scores = D1h.D2h^T + D1h.D2m^T + D1m.D2h^T   (error ~2^-22 rel)
// Per ks: 60 KB tile (A 10pb + B 20pb, 2 planes) = 60 x 1KB chunks; waves 0-3
// stage 8 chunks, waves 4-7 stage 7. Counted vmcnt (8/7), raw s_barrier.
// LDS 120 KB dbuf -> 1 block/CU; per-wave compute identical to 160x160 version
// but per-block demand per output is halved (240 KB / 512 pairs).
__device__ __forceinline__ void stage_ks(
    const _Float16* __restrict__ ah, const _Float16* __restrict__ am,
    const _Float16* __restrict__ bh, const _Float16* __restrict__ bm,
    int bi, int bj, int ks, int wave, int lane, char* dst)
{
#pragma unroll
    for (int c = 0; c < 8; ++c) {
        int chunk = wave + (c << 3);          // 0..59 (+ gaps)
        if (chunk < 60) {
            int side = chunk >= 20;           // 0 = A, 1 = B
            int rem = side ? chunk - 20 : chunk;
            int nb = side ? 20 : 10;
            int plane = rem >= nb;
            int pb = plane ? rem - nb : rem;
            const _Float16* base = side ? (plane ? bm : bh) : (plane ? am : ah);
            int gpb = side ? (bj * 20 + pb) : (bi * 10 + pb);
            size_t off = ((size_t)gpb << 11) + (ks << 9) + (lane << 3);
            gload_lds16(base + off, dst + (chunk << 10));
        }
    }
}

__global__ __launch_bounds__(512, 2) void gemm_ls_kernel(
    const _Float16* __restrict__ ah_, const _Float16* __restrict__ am_,
    const _Float16* __restrict__ bh_, const _Float16* __restrict__ bm_,
    const int* __restrict__ v1, const int* __restrict__ v2,
    float* __restrict__ ls, float* __restrict__ lsT)
{
    __shared__ __align__(16) char smem[122880];  // 2 x 60KB staging; epilogue overlays
    int tid = threadIdx.x;
    int wave = tid >> 6, lane = tid & 63;
    int wr = wave >> 2, wc = wave & 3;           // 2 x 4 wave grid

    // 2-D XCD tiling over the 32(bi) x 16(bj) grid: XCD owns 8x8 sub-grid.
    int flat = blockIdx.x;                       // 0..511
    int xcd = flat & 7, n = flat >> 3;           // n: 0..63
    int bi = (xcd >> 1) * 8 + (n >> 3);          // 0..31 (16 lines each)
    int bj = (xcd & 1) * 8 + (n & 7);            // 0..15 (32 lines each)

    int fro = ((lane >> 4) << 8) + ((lane & 15) << 4);  // byte offset inside a chunk

    f32x4 zz = {0.0f, 0.0f, 0.0f, 0.0f};
    f32x4 acc[5][5];
#pragma unroll
    for (int i = 0; i < 5; ++i)
#pragma unroll
        for (int j = 0; j < 5; ++j) acc[i][j] = zz;

    stage_ks(ah_, am_, bh_, bm_, bi, bj, 0, wave, lane, smem);  // prologue

#pragma unroll 1
    for (int ks = 0; ks < 4; ++ks) {
        char* buf = smem + ((ks & 1) ? 61440 : 0);
        if (ks < 3) {
            stage_ks(ah_, am_, bh_, bm_, bi, bj, ks + 1, wave, lane,
                     smem + (((ks + 1) & 1) ? 61440 : 0));
            if (wave < 4) asm volatile("s_waitcnt vmcnt(8)" ::: "memory");
            else          asm volatile("s_waitcnt vmcnt(7)" ::: "memory");
        } else {
            asm volatile("s_waitcnt vmcnt(0)" ::: "memory");
        }
        __builtin_amdgcn_sched_barrier(0);
        __builtin_amdgcn_s_barrier();
        __builtin_amdgcn_sched_barrier(0);

        f16x8 B0[5], B1[5];
#pragma unroll
        for (int j = 0; j < 5; ++j) {
            int pb = wc * 5 + j;                 // 0..19
            B0[j] = *(const f16x8*)(buf + ((20 + pb) << 10) + fro);
            B1[j] = *(const f16x8*)(buf + ((40 + pb) << 10) + fro);
        }
#pragma unroll
        for (int i = 0; i < 5; ++i) {
            int pb = wr * 5 + i;                 // 0..9
            f16x8 fh = *(const f16x8*)(buf + (pb << 10) + fro);
            f16x8 fm = *(const f16x8*)(buf + ((10 + pb) << 10) + fro);
#pragma unroll
            for (int j = 0; j < 5; ++j) {
                f32x4 t = acc[i][j];
                t = __builtin_amdgcn_mfma_f32_16x16x32_f16(fh, B0[j], t, 0, 0, 0);
                t = __builtin_amdgcn_mfma_f32_16x16x32_f16(fh, B1[j], t, 0, 0, 0);
                t = __builtin_amdgcn_mfma_f32_16x16x32_f16(fm, B0[j], t, 0, 0, 0);
                acc[i][j] = t;
            }
        }
        __builtin_amdgcn_sched_barrier(0);
        __builtin_amdgcn_s_barrier();
        __builtin_amdgcn_sched_barrier(0);
    }

    // ---- fused line-score epilogue: two phases (waves wr==half active) ----
    float* scr = (float*)smem;  // overlays dead staging (needs 103.4 KB < 120)
    const float rescale = 1.0f / 65536.0f;
    for (int half = 0; half < 2; ++half) {
        __syncthreads();
        if (wr == half) {
            float* reg = scr + wc * 6464;  // 64 pairs * 101 floats, per active wave
#pragma unroll
            for (int i = 0; i < 5; ++i)
#pragma unroll
                for (int j = 0; j < 5; ++j)
#pragma unroll
                    for (int r = 0; r < 4; ++r) {
                        int row = i * 16 + ((lane >> 4) << 2) + r;  // 0..79
                        int col = j * 16 + (lane & 15);             // 0..79
                        int pi = row / 10, s = row - pi * 10;
                        int pj = col / 10, t = col - pj * 10;
                        reg[(pi * 8 + pj) * 101 + s * 10 + t] = acc[i][j][r] * rescale;
                    }
            asm volatile("s_waitcnt lgkmcnt(0)" ::: "memory");
            // one lane owns one 10x10 line-pair (pair index == lane)
            const float* mp = reg + lane * 101;
            int iL = bi * 16 + half * 8 + (lane >> 3);
            int jL = bj * 32 + wc * 8 + (lane & 7);
            int va[10], vb[10];
#pragma unroll
            for (int s = 0; s < 10; ++s) va[s] = v1[iL * 10 + s];
#pragma unroll
            for (int t = 0; t < 10; ++t) vb[t] = v2[jL * 10 + t];
            float cmx[10];
#pragma unroll
            for (int t = 0; t < 10; ++t) cmx[t] = -3.0e38f;
            float sum1 = 0.0f; int c1 = 0;
#pragma unroll
            for (int s = 0; s < 10; ++s) {
                float rmx = -3.0e38f;
#pragma unroll
                for (int t = 0; t < 10; ++t) {
                    float v = (va[s] && vb[t]) ? mp[s * 10 + t] : -1.0f;
                    rmx = fmaxf(rmx, v);
                    cmx[t] = fmaxf(cmx[t], v);
                }
                if (rmx != -1.0f) { sum1 += rmx; c1++; }
            }
            float sum2 = 0.0f; int c2 = 0;
#pragma unroll
            for (int t = 0; t < 10; ++t) {
                if (cmx[t] != -1.0f) { sum2 += cmx[t]; c2++; }
            }
            float out = (sum1 / (float)c1 + sum2 / (float)c2) * 0.5f;
            ls[(size_t)iL * NL + jL] = out;
            lsT[(size_t)jL * NL + iL] = out;
        }
    }
}

// ---------------- NW with fused per-row top-10 ----------------
// Block (L,dir): wave 0 extracts the row's top-10 (stable-argsort tail
// semantics), writes topk for final_kernel; then stage-once + parallel dots
// + 20-thread DP as before.
__global__ __launch_bounds__(256) void nw_kernel(
    const float* __restrict__ d1, const float* __restrict__ d2,
    const int* __restrict__ v1, const int* __restrict__ v2,
    const float* __restrict__ ls, const float* __restrict__ lsT,
    int* __restrict__ topkg, float* __restrict__ nwout)
{
    int L = blockIdx.x;
    int dir = blockIdx.y;
    const float* Ad = dir ? d2 : d1;
    const float* Bd = dir ? d1 : d2;
    const int* vA = dir ? v2 : v1;
    const int* vB = dir ? v1 : v2;
    const float* src = dir ? &lsT[(size_t)L * NL] : &ls[(size_t)L * NL];

    __shared__ float Asl[10 * 132];       // 5.3 KB
    __shared__ float Bsl[10][1320];       // 52.8 KB
    __shared__ float M[10][110];          // [cand][s*11+t]
    __shared__ int vam[10], tks[10];

    int tid = threadIdx.x;
    if (tid < 10) vam[tid] = vA[L * 10 + tid];
#pragma unroll
    for (int it = 0; it < 5; ++it) {
        int idx = tid + it * 256;
        int row = idx >> 7, col = idx & 127;
        Asl[row * 132 + col] = Ad[((size_t)L * 10 + row) * DD + col];
    }
    // wave 0: top-10 extraction over the 512-wide row
    if (tid < 64) {
        int lane = tid;
        float v[8];
#pragma unroll
        for (int it = 0; it < 8; ++it) v[it] = src[it * 64 + lane];
        for (int p = 9; p >= 0; --p) {
            float bv = -3.0e38f;
            int bi_ = -1;
#pragma unroll
            for (int it = 0; it < 8; ++it) {
                int j = it * 64 + lane;
                bool better = (v[it] > bv) || (v[it] == bv && j > bi_);
                if (better) { bv = v[it]; bi_ = j; }
            }
#pragma unroll
            for (int m = 1; m < 64; m <<= 1) {
                float ov = __shfl_xor(bv, m);
                int oi = __shfl_xor(bi_, m);
                bool better = (ov > bv) || (ov == bv && oi > bi_);
                if (better) { bv = ov; bi_ = oi; }
            }
            if ((bi_ & 63) == lane) v[bi_ >> 6] = -3.0e38f;
            if (lane == 0) tks[p] = bi_;
        }
    }
    __syncthreads();
    if (tid < 10) topkg[(size_t)(dir * NL + L) * 10 + tid] = tks[tid];
#pragma unroll
    for (int it = 0; it < 50; ++it) {
        int idx = tid + it * 256;
        int c = idx / 1280;
        int rem = idx - c * 1280;
        int row = rem >> 7, col = rem & 127;
        Bsl[c][row * 132 + col] = Bd[((size_t)tks[c] * 10 + row) * DD + col];
    }
    __syncthreads();
#pragma unroll
    for (int it = 0; it < 4; ++it) {
        int w = tid + it * 256;
        if (w < 1000) {
            int c = w / 100;
            int rem = w - c * 100;
            int s = rem / 10, t = rem - s * 10;
            const float4* ap = (const float4*)&Asl[s * 132];
            const float4* bp = (const float4*)&Bsl[c][t * 132];
            float acc = 0.0f;
#pragma unroll
            for (int k = 0; k < 32; ++k) {
                float4 a = ap[k], b = bp[k];
                acc = fmaf(a.x, b.x, acc);
                acc = fmaf(a.y, b.y, acc);
                acc = fmaf(a.z, b.z, acc);
                acc = fmaf(a.w, b.w, acc);
            }
            int ok = vam[s] && vB[tks[c] * 10 + t];
            M[c][s * 11 + t] = ok ? acc : -1.0f;
        }
    }
    __syncthreads();

    if (tid < 20) {
        int c = tid % 10, f = tid / 10;
        float prev[11];
#pragma unroll
        for (int p = 0; p < 11; ++p) prev[p] = 0.0f;
#pragma unroll
        for (int s = 0; s < 10; ++s) {
            float oldp = prev[0];
            float run = -3.0e38f;
#pragma unroll
            for (int t = 0; t < 10; ++t) {
                int tt = f ? (9 - t) : t;
                float sc = M[c][s * 11 + tt] - 0.1f;
                float pt1 = prev[t + 1];
                float av = fmaxf(pt1, oldp + sc);
                run = fmaxf(run, av);
                prev[t + 1] = fmaxf(run, 0.0f);
                oldp = pt1;
            }
        }
        nwout[((size_t)(dir * NL + L)) * 20 + f * 10 + c] = prev[10];
    }
}

// ---------------- argmax + mutual check ----------------
__global__ __launch_bounds__(512) void final_kernel(
    const float* __restrict__ nw, const int* __restrict__ topk, int* __restrict__ out)
{
    __shared__ int m1[NL], m2[NL];
    int t = threadIdx.x;
    {
        const float* p = nw + (size_t)t * 20;
        float bb = -3.0e38f; int kk = 0;
        for (int k = 0; k < 20; ++k) {
            float v = p[k];
            if (v > bb) { bb = v; kk = k; }
        }
        m1[t] = topk[(size_t)t * 10 + (kk % 10)];
    }
    {
        const float* p = nw + (size_t)(NL + t) * 20;
        float bb = -3.0e38f; int kk = 0;
        for (int k = 0; k < 20; ++k) {
            float v = p[k];
            if (v > bb) { bb = v; kk = k; }
        }
        m2[t] = topk[(size_t)(NL + t) * 10 + (kk % 10)];
    }
    __syncthreads();
    int mt = m1[t];
    out[t] = (m2[mt] == t) ? mt : -1;
}

extern "C" void kernel_launch(void* const* d_in, const int* in_sizes, int n_in,
                              void* d_out, int out_size, void* d_ws, size_t ws_size,
                              hipStream_t stream)
{
    const float* seg1 = (const float*)d_in[0];
    const float* seg2 = (const float*)d_in[1];
    const float* desc1 = (const float*)d_in[2];
    const float* desc2 = (const float*)d_in[3];
    int* out = (int*)d_out;

    char* ws = (char*)d_ws;
    size_t off = 0;
    float* dt1 = (float*)(ws + off); off += (size_t)DD * HWC * 4;        // 8 MB
    float* dt2 = (float*)(ws + off); off += (size_t)DD * HWC * 4;        // 8 MB
    float* dd1 = (float*)(ws + off); off += (size_t)NL * SS * DD * 4;    // 2.5 MB
    float* dd2 = (float*)(ws + off); off += (size_t)NL * SS * DD * 4;    // 2.5 MB
    int* v1 = (int*)(ws + off); off += (size_t)NL * SS * 4;
    int* v2 = (int*)(ws + off); off += (size_t)NL * SS * 4;
    float* ls = (float*)(ws + off); off += (size_t)NL * NL * 4;          // 1 MB
    float* lsT = (float*)(ws + off); off += (size_t)NL * NL * 4;         // 1 MB
    int* topk = (int*)(ws + off); off += (size_t)2 * NL * 10 * 4;
    float* nwv = (float*)(ws + off); off += (size_t)2 * NL * 20 * 4;
    size_t PL = (size_t)NL * SS * DD;                                    // 655360 elems
    _Float16* h1 = (_Float16*)(ws + off); off += PL * 2;                 // 1.25 MB each
    _Float16* m1 = (_Float16*)(ws + off); off += PL * 2;
    _Float16* h2 = (_Float16*)(ws + off); off += PL * 2;
    _Float16* m2 = (_Float16*)(ws + off); off += PL * 2;

    transpose_kernel<<<dim3(HWC / 32, DD / 32, 2), dim3(32, 8), 0, stream>>>(
        desc1, desc2, dt1, dt2);
    sample_kernel<<<dim3(NL, 2), 640, 0, stream>>>(
        seg1, seg2, dt1, dt2, dd1, dd2, h1, m1, h2, m2, v1, v2);
    gemm_ls_kernel<<<512, 512, 0, stream>>>(
        h1, m1, h2, m2, v1, v2, ls, lsT);
    nw_kernel<<<dim3(NL, 2), 256, 0, stream>>>(
        dd1, dd2, v1, v2, ls, lsT, topk, nwv);
    final_kernel<<<1, 512, 0, stream>>>(nwv, topk, out);
}